// Round 1
// baseline (1301.060 us; speedup 1.0000x reference)
//
#include <hip/hip_runtime.h>
#include <cstdint>
#include <cstddef>

#define DI __device__ __forceinline__

typedef unsigned short u16;

// ---------------- problem constants ----------------
constexpr int B_ = 2, T_ = 1024, C_ = 2048, H_ = 32, N_ = 64;
constexpr int BT = B_ * T_;            // 2048 rows
constexpr float GN_EPS_C = 64e-5f;     // N * 1e-5

// ---------------- small helpers ----------------
DI float bf2f(u16 h) {
    union { unsigned u; float f; } x; x.u = ((unsigned)h) << 16; return x.f;
}
DI u16 f2bf(float f) {
    union { float f; unsigned u; } x; x.f = f;
    unsigned r = (x.u + 0x7fffu + ((x.u >> 16) & 1u)) >> 16;
    return (u16)r;
}
DI float rdlane(float v, int l) {
    union { float f; int i; } x; x.f = v;
    x.i = __builtin_amdgcn_readlane(x.i, l);
    return x.f;
}
DI float sigmoidf_(float x) { return 1.f / (1.f + __expf(-x)); }

typedef __attribute__((ext_vector_type(8))) __bf16 bf16x8;
typedef __attribute__((ext_vector_type(4))) float f32x4;

DI void gload16(const void* g, void* l) {
    __builtin_amdgcn_global_load_lds(
        (const __attribute__((address_space(1))) void*)g,
        (__attribute__((address_space(3))) void*)l,
        16, 0, 0);
}

// ---------------- epilogue ids ----------------
enum { EP_BF16 = 0, EP_F32 = 1, EP_TANH = 2, EP_SIG = 3, EP_DECAY = 4, EP_ASIG = 5, EP_VMIX = 6 };

// ---------------- generic 128x128x32 bf16 MFMA GEMM core (m97 recipe) ----------------
// A: bf16 [M,K] row-major (lda), Bt: bf16 [N,K] row-major (ldb)  ->  Out[m,n] (ldc)
DI void gemm_core(const u16* __restrict__ A, int lda,
                  const u16* __restrict__ Bt, int ldb,
                  void* __restrict__ Out, int ldc,
                  int Nreal, int K, int m0, int n0, int epi,
                  const float* __restrict__ aux0, const float* __restrict__ aux1) {
    __shared__ u16 lA[128 * 32];
    __shared__ u16 lB[128 * 32];
    const int tid = threadIdx.x;
    const int lane = tid & 63;
    const int wv = tid >> 6;
    const int wr = wv >> 1, wc = wv & 1;
    const int r0 = tid >> 2;            // staging row 0..63
    const int cc0 = (tid & 3) * 8;      // staging k-offset (elements)

    f32x4 acc[4][4];
#pragma unroll
    for (int i = 0; i < 4; i++)
#pragma unroll
        for (int j = 0; j < 4; j++) acc[i][j] = (f32x4){0.f, 0.f, 0.f, 0.f};

    const u16* Abase = A + (size_t)(m0 + r0) * lda + cc0;
    const u16* Bbase = Bt + (size_t)(n0 + r0) * ldb + cc0;
    u16* lA0 = &lA[r0 * 32 + cc0];
    u16* lA1 = &lA[(r0 + 64) * 32 + cc0];
    u16* lB0 = &lB[r0 * 32 + cc0];
    u16* lB1 = &lB[(r0 + 64) * 32 + cc0];

    for (int k0 = 0; k0 < K; k0 += 32) {
        __syncthreads();
        gload16(Abase + k0, lA0);
        gload16(Abase + (size_t)64 * lda + k0, lA1);
        gload16(Bbase + k0, lB0);
        gload16(Bbase + (size_t)64 * ldb + k0, lB1);
        __syncthreads();
        bf16x8 af[4], bfr[4];
#pragma unroll
        for (int i = 0; i < 4; i++) {
            af[i]  = *(const bf16x8*)&lA[(wr * 64 + i * 16 + (lane & 15)) * 32 + (lane >> 4) * 8];
            bfr[i] = *(const bf16x8*)&lB[(wc * 64 + i * 16 + (lane & 15)) * 32 + (lane >> 4) * 8];
        }
#pragma unroll
        for (int mi = 0; mi < 4; mi++)
#pragma unroll
            for (int ni = 0; ni < 4; ni++)
                acc[mi][ni] = __builtin_amdgcn_mfma_f32_16x16x32_bf16(af[mi], bfr[ni], acc[mi][ni], 0, 0, 0);
    }

    // epilogue: C/D layout col=lane&15, row=(lane>>4)*4+reg (m89-verified)
#pragma unroll
    for (int mi = 0; mi < 4; mi++) {
#pragma unroll
        for (int ni = 0; ni < 4; ni++) {
            int n = n0 + wc * 64 + ni * 16 + (lane & 15);
            if (n >= Nreal) continue;
#pragma unroll
            for (int rg = 0; rg < 4; rg++) {
                int m = m0 + wr * 64 + mi * 16 + (lane >> 4) * 4 + rg;
                size_t ix = (size_t)m * ldc + n;
                float f = acc[mi][ni][rg];
                switch (epi) {
                    case EP_BF16: ((u16*)Out)[ix] = f2bf(f); break;
                    case EP_F32:  ((float*)Out)[ix] = f; break;
                    case EP_TANH: ((u16*)Out)[ix] = f2bf(tanhf(f)); break;
                    case EP_SIG:  ((u16*)Out)[ix] = f2bf(sigmoidf_(f)); break;
                    case EP_DECAY: {
                        float z = -(aux0[n] + f);
                        float sp = (z > 15.f) ? z : log1pf(expf(z));
                        ((float*)Out)[ix] = expf(-expf(-0.5f - sp));
                    } break;
                    case EP_ASIG: ((u16*)Out)[ix] = f2bf(sigmoidf_(aux0[n] + f)); break;
                    case EP_VMIX: {
                        float vs = sigmoidf_(aux0[n] + f);
                        float old = bf2f(((u16*)Out)[ix]);
                        float vf = aux1[ix];
                        ((u16*)Out)[ix] = f2bf(old + (vf - old) * vs);
                    } break;
                }
            }
        }
    }
}

__global__ __launch_bounds__(256, 1) void k_gemm(const u16* A, int lda, const u16* Bt, int ldb,
                                                 void* Out, int ldc, int Nreal, int K, int epi,
                                                 const float* aux0, const float* aux1) {
    gemm_core(A, lda, Bt, ldb, Out, ldc, Nreal, K, blockIdx.y * 128, blockIdx.x * 128, epi, aux0, aux1);
}

__global__ __launch_bounds__(256, 1) void k_gemm_rkv(const u16* xmix, const u16* WrT, const u16* WkT,
                                                     const u16* WvT, u16* rb, u16* kb, u16* vb) {
    int z = blockIdx.z;
    const int sel[3] = {0, 2, 3};  // xr, xk, xv
    const u16* A = xmix + (size_t)sel[z] * BT * C_;
    const u16* Bt = (z == 0) ? WrT : (z == 1) ? WkT : WvT;
    u16* Out = (z == 0) ? rb : (z == 1) ? kb : vb;
    gemm_core(A, C_, Bt, C_, Out, C_, C_, C_, blockIdx.y * 128, blockIdx.x * 128, EP_BF16, nullptr, nullptr);
}

__global__ __launch_bounds__(256, 1) void k_upproj(const u16* xmix, const u16* w1T, const u16* a1T,
                                                   const u16* v1T, const u16* g1T, u16* hbuf) {
    int z = blockIdx.z;
    int n0 = blockIdx.x * 128;
    const int npad[4]  = {128, 128, 128, 256};
    if (n0 >= npad[z]) return;
    const int sel[4]   = {1, 4, 3, 5};        // xw, xa, xv, xg
    const int nreal[4] = {96, 96, 64, 256};
    const int coff[4]  = {0, 96, 192, 256};
    const int epi[4]   = {EP_TANH, EP_BF16, EP_BF16, EP_SIG};
    const u16* Bt = (z == 0) ? w1T : (z == 1) ? a1T : (z == 2) ? v1T : g1T;
    gemm_core(xmix + (size_t)sel[z] * BT * C_, C_, Bt, C_, hbuf + coff[z], 512, nreal[z], C_,
              blockIdx.y * 128, n0, epi[z], nullptr, nullptr);
}

// ---------------- weight transpose + bf16 convert ----------------
struct TDesc { const float* in; u16* out; int K; int N; };
struct TArgs { TDesc d[12]; };

__global__ void k_transpose(TArgs a) {
    TDesc dd = a.d[blockIdx.z];
    int k0 = blockIdx.x * 32, n0 = blockIdx.y * 32;
    if (k0 >= dd.K || n0 >= dd.N) return;
    __shared__ float tile[32][33];
    int tx = threadIdx.x & 31, ty = threadIdx.x >> 5;  // ty 0..7
#pragma unroll
    for (int i = 0; i < 32; i += 8)
        tile[ty + i][tx] = dd.in[(size_t)(k0 + ty + i) * dd.N + (n0 + tx)];
    __syncthreads();
#pragma unroll
    for (int i = 0; i < 32; i += 8)
        dd.out[(size_t)(n0 + ty + i) * dd.K + (k0 + tx)] = f2bf(tile[tx][ty + i]);
}

// ---------------- token-shift mixing (6 outputs, bf16) ----------------
__global__ void k_mix(const float* __restrict__ x, const float* cr, const float* cw, const float* ck,
                      const float* cv, const float* ca, const float* cg, u16* __restrict__ xmix) {
    int idx = blockIdx.x * 256 + threadIdx.x;   // < BT*C
    int c = idx & (C_ - 1);
    int bt = idx >> 11;
    int t = bt & (T_ - 1);
    float xv = x[idx];
    float xp = (t == 0) ? 0.f : x[idx - C_];
    float dx = xp - xv;
    const size_t S = (size_t)BT * C_;
    xmix[0 * S + idx] = f2bf(xv + dx * cr[c]);
    xmix[1 * S + idx] = f2bf(xv + dx * cw[c]);
    xmix[2 * S + idx] = f2bf(xv + dx * ck[c]);
    xmix[3 * S + idx] = f2bf(xv + dx * cv[c]);
    xmix[4 * S + idx] = f2bf(xv + dx * ca[c]);
    xmix[5 * S + idx] = f2bf(xv + dx * cg[c]);
}

// ---------------- head prep: kk normalize + k modulation ----------------
__global__ void k_headprep(u16* __restrict__ kb, const u16* __restrict__ ab,
                           const float* __restrict__ k_k, const float* __restrict__ k_a,
                           u16* __restrict__ kkb) {
    int g = blockIdx.x * 4 + (threadIdx.x >> 6);     // bt*H + h
    int lane = threadIdx.x & 63;
    size_t ix = (size_t)g * 64 + lane;
    int c = (g & (H_ - 1)) * 64 + lane;
    float kraw = bf2f(kb[ix]);
    float av = bf2f(ab[ix]);
    float kkv = kraw * k_k[c];
    float ss = kkv * kkv;
#pragma unroll
    for (int m = 32; m >= 1; m >>= 1) ss += __shfl_xor(ss, m, 64);
    float inv = 1.f / fmaxf(sqrtf(ss), 1e-12f);
    kkb[ix] = f2bf(kkv * inv);
    kb[ix] = f2bf(kraw * (1.f + (av - 1.f) * k_a[c]));
}

// ---------------- WKV7 sequential scan ----------------
// 64 blocks (b*H+h), 256 threads = 4 waves. lane = state row v; wave wv owns k-slice [16*wv,16*wv+16).
// Per-step shared vectors staged to LDS 32 steps at a time with global_load_lds.
#define SCHUNK 32
__global__ __launch_bounds__(256, 1) void k_scan(
    const u16* __restrict__ rb, const float* __restrict__ wd,
    const u16* __restrict__ kb, const u16* __restrict__ vb,
    const u16* __restrict__ kkb, const u16* __restrict__ ab,
    float* __restrict__ yout) {
    __shared__ u16 s_r[2][SCHUNK * 64], s_k[2][SCHUNK * 64], s_v[2][SCHUNK * 64],
                   s_kk[2][SCHUNK * 64], s_as[2][SCHUNK * 64];
    __shared__ float s_w[2][SCHUNK * 64];
    __shared__ float sabuf[256], ybuf[256];

    const int tid = threadIdx.x, wv = tid >> 6, lane = tid & 63;
    const int bh = blockIdx.x;
    const int b = bh >> 5, h = bh & 31;
    const size_t base0 = ((size_t)b * T_ * H_ + h) * 64;

    float S[16];
#pragma unroll
    for (int j = 0; j < 16; j++) S[j] = 0.f;

    auto stage = [&](int ci, int buf) {
        int c0 = ci * SCHUNK;
        {   // bf16 arrays: wave wv covers step rows [wv*8, wv*8+8), 8 lanes/row * 16B
            int sloc = wv * 8 + (lane >> 3);
            int e8 = (lane & 7) * 8;
            size_t g = base0 + (size_t)(c0 + sloc) * C_ + e8;
            int loff = sloc * 64 + e8;
            gload16(rb + g,  &s_r[buf][loff]);
            gload16(kb + g,  &s_k[buf][loff]);
            gload16(vb + g,  &s_v[buf][loff]);
            gload16(kkb + g, &s_kk[buf][loff]);
            gload16(ab + g,  &s_as[buf][loff]);
        }
#pragma unroll
        for (int j = 0; j < 2; j++) {   // f32 decay: 16 lanes/row
            int q = wv * 2 + j;
            int sloc = q * 4 + (lane >> 4);
            int e4 = (lane & 15) * 4;
            size_t g = base0 + (size_t)(c0 + sloc) * C_ + e4;
            gload16(wd + g, &s_w[buf][sloc * 64 + e4]);
        }
    };

    stage(0, 0);
    __syncthreads();

    for (int ci = 0; ci < T_ / SCHUNK; ci++) {
        int cur = ci & 1;
        int cn = (ci + 1 < T_ / SCHUNK) ? ci + 1 : ci;
        stage(cn, 1 - cur);
        for (int s = 0; s < SCHUNK; s++) {
            int sl = s * 64 + lane;
            float r_l  = bf2f(s_r[cur][sl]);
            float k_l  = bf2f(s_k[cur][sl]);
            float vt   = bf2f(s_v[cur][sl]);
            float kk_l = bf2f(s_kk[cur][sl]);
            float as_l = bf2f(s_as[cur][sl]);
            float w_l  = s_w[cur][sl];
            float a_l = -kk_l;
            float b_l = kk_l * as_l;

            float sa0 = 0.f, sa1 = 0.f;
#pragma unroll
            for (int j = 0; j < 16; j += 2) {
                sa0 += S[j]     * rdlane(a_l, wv * 16 + j);
                sa1 += S[j + 1] * rdlane(a_l, wv * 16 + j + 1);
            }
            sabuf[lane * 4 + wv] = sa0 + sa1;
            __syncthreads();
            const float4 sp = *(const float4*)&sabuf[lane * 4];
            float sa = (sp.x + sp.y) + (sp.z + sp.w);

            float y0 = 0.f, y1 = 0.f;
#pragma unroll
            for (int j = 0; j < 16; j++) {
                int kq = wv * 16 + j;
                float sw = rdlane(w_l, kq);
                float sk = rdlane(k_l, kq);
                float sb = rdlane(b_l, kq);
                float sr = rdlane(r_l, kq);
                float sv_ = S[j] * sw + sa * sb + vt * sk;
                S[j] = sv_;
                if (j & 1) y1 += sv_ * sr; else y0 += sv_ * sr;
            }
            ybuf[lane * 4 + wv] = y0 + y1;
            __syncthreads();
            if (wv == 0) {
                const float4 yp = *(const float4*)&ybuf[lane * 4];
                yout[base0 + (size_t)(ci * SCHUNK + s) * C_ + lane] = (yp.x + yp.y) + (yp.z + yp.w);
            }
        }
    }
}

// ---------------- GroupNorm + bonus + gate ----------------
__global__ void k_gn(const float* __restrict__ y, const u16* __restrict__ rb, const u16* __restrict__ kb,
                     const u16* __restrict__ vb, const u16* __restrict__ gb,
                     const float* __restrict__ gn_w, const float* __restrict__ gn_b,
                     const float* __restrict__ r_k, u16* __restrict__ yg) {
    int g = blockIdx.x * 4 + (threadIdx.x >> 6);     // bt*H + h
    int lane = threadIdx.x & 63;
    size_t ix = (size_t)g * 64 + lane;
    int c = (g & (H_ - 1)) * 64 + lane;
    float yv = y[ix];
    float rv = bf2f(rb[ix]), kv = bf2f(kb[ix]);
    float m1 = yv, m2 = yv * yv, s = rv * kv * r_k[c];
#pragma unroll
    for (int m = 32; m >= 1; m >>= 1) {
        m1 += __shfl_xor(m1, m, 64);
        m2 += __shfl_xor(m2, m, 64);
        s  += __shfl_xor(s, m, 64);
    }
    m1 *= (1.f / 64.f);
    m2 *= (1.f / 64.f);
    float var = m2 - m1 * m1;
    float xn = (yv - m1) * rsqrtf(var + GN_EPS_C);
    xn = xn * gn_w[c] + gn_b[c];
    float out = (xn + s * bf2f(vb[ix])) * bf2f(gb[ix]);
    yg[ix] = f2bf(out);
}

// ---------------- launcher ----------------
extern "C" void kernel_launch(void* const* d_in, const int* in_sizes, int n_in,
                              void* d_out, int out_size, void* d_ws, size_t ws_size,
                              hipStream_t stream) {
    const float* x      = (const float*)d_in[0];
    const float* vfirst = (const float*)d_in[1];
    const float* x_r = (const float*)d_in[2];
    const float* x_w = (const float*)d_in[3];
    const float* x_k = (const float*)d_in[4];
    const float* x_v = (const float*)d_in[5];
    const float* x_a = (const float*)d_in[6];
    const float* x_g = (const float*)d_in[7];
    const float* w0 = (const float*)d_in[8];
    const float* w1 = (const float*)d_in[9];
    const float* w2 = (const float*)d_in[10];
    const float* a0 = (const float*)d_in[11];
    const float* a1 = (const float*)d_in[12];
    const float* a2 = (const float*)d_in[13];
    const float* v0 = (const float*)d_in[14];
    const float* v1 = (const float*)d_in[15];
    const float* v2 = (const float*)d_in[16];
    const float* g1 = (const float*)d_in[17];
    const float* g2 = (const float*)d_in[18];
    const float* k_k = (const float*)d_in[19];
    const float* k_a = (const float*)d_in[20];
    const float* r_k = (const float*)d_in[21];
    const float* W_r = (const float*)d_in[22];
    const float* W_k = (const float*)d_in[23];
    const float* W_v = (const float*)d_in[24];
    const float* W_o = (const float*)d_in[25];
    const float* gn_w = (const float*)d_in[26];
    const float* gn_b = (const float*)d_in[27];
    (void)in_sizes; (void)n_in; (void)out_size; (void)ws_size;

    char* wsp = (char*)d_ws;
    size_t off = 0;
    auto alloc = [&](size_t bytes) -> char* {
        char* p = wsp + off;
        off += (bytes + 255) & ~(size_t)255;
        return p;
    };
    const size_t MAT = (size_t)BT * C_;  // 4M elements

    u16* WrT = (u16*)alloc(MAT * 2);
    u16* WkT = (u16*)alloc(MAT * 2);
    u16* WvT = (u16*)alloc(MAT * 2);
    u16* WoT = (u16*)alloc(MAT * 2);
    u16* w1T = (u16*)alloc((size_t)128 * 2048 * 2);
    u16* a1T = (u16*)alloc((size_t)128 * 2048 * 2);
    u16* v1T = (u16*)alloc((size_t)128 * 2048 * 2);
    u16* g1T = (u16*)alloc((size_t)256 * 2048 * 2);
    u16* w2T = (u16*)alloc((size_t)2048 * 96 * 2);
    u16* a2T = (u16*)alloc((size_t)2048 * 96 * 2);
    u16* v2T = (u16*)alloc((size_t)2048 * 64 * 2);
    u16* g2T = (u16*)alloc((size_t)2048 * 256 * 2);
    u16* xmix = (u16*)alloc(6 * MAT * 2);
    u16* hbuf = (u16*)alloc((size_t)BT * 512 * 2);
    u16* rbuf = (u16*)alloc(MAT * 2);
    u16* kbuf = (u16*)alloc(MAT * 2);
    u16* vbuf = (u16*)alloc(MAT * 2);
    u16* kkbuf = (u16*)alloc(MAT * 2);
    u16* asig = (u16*)alloc(MAT * 2);
    float* wdec = (float*)alloc(MAT * 4);
    u16* gbuf = (u16*)alloc(MAT * 2);
    float* ybuf = (float*)alloc(MAT * 4);
    u16* ygbuf = (u16*)alloc(MAT * 2);

    // 1) weight transposes (fp32 -> bf16 [N,K])
    TArgs ta;
    ta.d[0]  = {W_r, WrT, 2048, 2048};
    ta.d[1]  = {W_k, WkT, 2048, 2048};
    ta.d[2]  = {W_v, WvT, 2048, 2048};
    ta.d[3]  = {W_o, WoT, 2048, 2048};
    ta.d[4]  = {w1, w1T, 2048, 96};
    ta.d[5]  = {a1, a1T, 2048, 96};
    ta.d[6]  = {v1, v1T, 2048, 64};
    ta.d[7]  = {g1, g1T, 2048, 256};
    ta.d[8]  = {w2, w2T, 96, 2048};
    ta.d[9]  = {a2, a2T, 96, 2048};
    ta.d[10] = {v2, v2T, 64, 2048};
    ta.d[11] = {g2, g2T, 256, 2048};
    k_transpose<<<dim3(64, 64, 12), 256, 0, stream>>>(ta);

    // 2) token-shift mixes
    k_mix<<<dim3((unsigned)(MAT / 256)), 256, 0, stream>>>(x, x_r, x_w, x_k, x_v, x_a, x_g, xmix);

    // 3) LoRA up-projections (tanh / none / none / sigmoid) into hbuf
    k_upproj<<<dim3(2, 16, 4), 256, 0, stream>>>(xmix, w1T, a1T, v1T, g1T, hbuf);

    // 4) big GEMMs r/k/v
    k_gemm_rkv<<<dim3(16, 16, 3), 256, 0, stream>>>(xmix, WrT, WkT, WvT, rbuf, kbuf, vbuf);

    // 5) LoRA down-projections with fused epilogues
    k_gemm<<<dim3(16, 16), 256, 0, stream>>>(hbuf + 0, 512, w2T, 96, wdec, 2048, 2048, 96, EP_DECAY, w0, nullptr);
    k_gemm<<<dim3(16, 16), 256, 0, stream>>>(hbuf + 96, 512, a2T, 96, asig, 2048, 2048, 96, EP_ASIG, a0, nullptr);
    k_gemm<<<dim3(16, 16), 256, 0, stream>>>(hbuf + 192, 512, v2T, 64, vbuf, 2048, 2048, 64, EP_VMIX, v0, vfirst);
    k_gemm<<<dim3(16, 16), 256, 0, stream>>>(hbuf + 256, 512, g2T, 256, gbuf, 2048, 2048, 256, EP_BF16, nullptr, nullptr);

    // 6) head prep: kk normalize + k modulation (in-place on kbuf)
    k_headprep<<<dim3(BT * H_ / 4), 256, 0, stream>>>(kbuf, asig, k_k, k_a, kkbuf);

    // 7) WKV7 scan
    k_scan<<<dim3(B_ * H_), 256, 0, stream>>>(rbuf, wdec, kbuf, vbuf, kkbuf, asig, ybuf);

    // 8) GroupNorm + bonus + gate
    k_gn<<<dim3(BT * H_ / 4), 256, 0, stream>>>(ybuf, rbuf, kbuf, vbuf, gbuf, gn_w, gn_b, r_k, ygbuf);

    // 9) output projection
    k_gemm<<<dim3(16, 16), 256, 0, stream>>>(ygbuf, 2048, WoT, 2048, d_out, 2048, 2048, 2048, EP_F32, nullptr, nullptr);
}

// Round 2
// 733.832 us; speedup vs baseline: 1.7730x; 1.7730x over previous
//
#include <hip/hip_runtime.h>
#include <cstdint>
#include <cstddef>

#define DI __device__ __forceinline__

typedef unsigned short u16;

// ---------------- problem constants ----------------
constexpr int B_ = 2, T_ = 1024, C_ = 2048, H_ = 32, N_ = 64;
constexpr int BT = B_ * T_;            // 2048 rows
constexpr float GN_EPS_C = 64e-5f;     // N * 1e-5
constexpr int LCH = 64;                // scan chunk length
constexpr int NC = T_ / LCH;           // 16 chunks
constexpr int UNITS = B_ * H_ * NC;    // 1024 (b,h,chunk) units

// ---------------- small helpers ----------------
DI float bf2f(u16 h) {
    union { unsigned u; float f; } x; x.u = ((unsigned)h) << 16; return x.f;
}
DI u16 f2bf(float f) {
    union { float f; unsigned u; } x; x.f = f;
    unsigned r = (x.u + 0x7fffu + ((x.u >> 16) & 1u)) >> 16;
    return (u16)r;
}
DI float sigmoidf_(float x) { return 1.f / (1.f + __expf(-x)); }

typedef __attribute__((ext_vector_type(8))) __bf16 bf16x8;
typedef __attribute__((ext_vector_type(4))) float f32x4;

DI void gload16(const void* g, void* l) {
    __builtin_amdgcn_global_load_lds(
        (const __attribute__((address_space(1))) void*)g,
        (__attribute__((address_space(3))) void*)l,
        16, 0, 0);
}

// ---------------- epilogue ids ----------------
enum { EP_BF16 = 0, EP_F32 = 1, EP_TANH = 2, EP_SIG = 3, EP_DECAY = 4, EP_ASIG = 5, EP_VMIX = 6 };

// ---------------- generic 128x128x32 bf16 MFMA GEMM core (m97 recipe) ----------------
DI void gemm_core(const u16* __restrict__ A, int lda,
                  const u16* __restrict__ Bt, int ldb,
                  void* __restrict__ Out, int ldc,
                  int Nreal, int K, int m0, int n0, int epi,
                  const float* __restrict__ aux0, const float* __restrict__ aux1) {
    __shared__ u16 lA[128 * 32];
    __shared__ u16 lB[128 * 32];
    const int tid = threadIdx.x;
    const int lane = tid & 63;
    const int wv = tid >> 6;
    const int wr = wv >> 1, wc = wv & 1;
    const int r0 = tid >> 2;
    const int cc0 = (tid & 3) * 8;

    f32x4 acc[4][4];
#pragma unroll
    for (int i = 0; i < 4; i++)
#pragma unroll
        for (int j = 0; j < 4; j++) acc[i][j] = (f32x4){0.f, 0.f, 0.f, 0.f};

    const u16* Abase = A + (size_t)(m0 + r0) * lda + cc0;
    const u16* Bbase = Bt + (size_t)(n0 + r0) * ldb + cc0;
    u16* lA0 = &lA[r0 * 32 + cc0];
    u16* lA1 = &lA[(r0 + 64) * 32 + cc0];
    u16* lB0 = &lB[r0 * 32 + cc0];
    u16* lB1 = &lB[(r0 + 64) * 32 + cc0];

    for (int k0 = 0; k0 < K; k0 += 32) {
        __syncthreads();
        gload16(Abase + k0, lA0);
        gload16(Abase + (size_t)64 * lda + k0, lA1);
        gload16(Bbase + k0, lB0);
        gload16(Bbase + (size_t)64 * ldb + k0, lB1);
        __syncthreads();
        bf16x8 af[4], bfr[4];
#pragma unroll
        for (int i = 0; i < 4; i++) {
            af[i]  = *(const bf16x8*)&lA[(wr * 64 + i * 16 + (lane & 15)) * 32 + (lane >> 4) * 8];
            bfr[i] = *(const bf16x8*)&lB[(wc * 64 + i * 16 + (lane & 15)) * 32 + (lane >> 4) * 8];
        }
#pragma unroll
        for (int mi = 0; mi < 4; mi++)
#pragma unroll
            for (int ni = 0; ni < 4; ni++)
                acc[mi][ni] = __builtin_amdgcn_mfma_f32_16x16x32_bf16(af[mi], bfr[ni], acc[mi][ni], 0, 0, 0);
    }

#pragma unroll
    for (int mi = 0; mi < 4; mi++) {
#pragma unroll
        for (int ni = 0; ni < 4; ni++) {
            int n = n0 + wc * 64 + ni * 16 + (lane & 15);
            if (n >= Nreal) continue;
#pragma unroll
            for (int rg = 0; rg < 4; rg++) {
                int m = m0 + wr * 64 + mi * 16 + (lane >> 4) * 4 + rg;
                size_t ix = (size_t)m * ldc + n;
                float f = acc[mi][ni][rg];
                switch (epi) {
                    case EP_BF16: ((u16*)Out)[ix] = f2bf(f); break;
                    case EP_F32:  ((float*)Out)[ix] = f; break;
                    case EP_TANH: ((u16*)Out)[ix] = f2bf(tanhf(f)); break;
                    case EP_SIG:  ((u16*)Out)[ix] = f2bf(sigmoidf_(f)); break;
                    case EP_DECAY: {
                        float z = -(aux0[n] + f);
                        float sp = (z > 15.f) ? z : log1pf(expf(z));
                        ((float*)Out)[ix] = expf(-expf(-0.5f - sp));
                    } break;
                    case EP_ASIG: ((u16*)Out)[ix] = f2bf(sigmoidf_(aux0[n] + f)); break;
                    case EP_VMIX: {
                        float vs = sigmoidf_(aux0[n] + f);
                        float old = bf2f(((u16*)Out)[ix]);
                        float vf = aux1[ix];
                        ((u16*)Out)[ix] = f2bf(old + (vf - old) * vs);
                    } break;
                }
            }
        }
    }
}

__global__ __launch_bounds__(256, 1) void k_gemm(const u16* A, int lda, const u16* Bt, int ldb,
                                                 void* Out, int ldc, int Nreal, int K, int epi,
                                                 const float* aux0, const float* aux1) {
    gemm_core(A, lda, Bt, ldb, Out, ldc, Nreal, K, blockIdx.y * 128, blockIdx.x * 128, epi, aux0, aux1);
}

__global__ __launch_bounds__(256, 1) void k_gemm_rkv(const u16* xmix, const u16* WrT, const u16* WkT,
                                                     const u16* WvT, u16* rb, u16* kb, u16* vb) {
    int z = blockIdx.z;
    const int sel[3] = {0, 2, 3};  // xr, xk, xv
    const u16* A = xmix + (size_t)sel[z] * BT * C_;
    const u16* Bt = (z == 0) ? WrT : (z == 1) ? WkT : WvT;
    u16* Out = (z == 0) ? rb : (z == 1) ? kb : vb;
    gemm_core(A, C_, Bt, C_, Out, C_, C_, C_, blockIdx.y * 128, blockIdx.x * 128, EP_BF16, nullptr, nullptr);
}

__global__ __launch_bounds__(256, 1) void k_upproj(const u16* xmix, const u16* w1T, const u16* a1T,
                                                   const u16* v1T, const u16* g1T, u16* hbuf) {
    int z = blockIdx.z;
    int n0 = blockIdx.x * 128;
    const int npad[4]  = {128, 128, 128, 256};
    if (n0 >= npad[z]) return;
    const int sel[4]   = {1, 4, 3, 5};        // xw, xa, xv, xg
    const int nreal[4] = {96, 96, 64, 256};
    const int coff[4]  = {0, 96, 192, 256};
    const int epi[4]   = {EP_TANH, EP_BF16, EP_BF16, EP_SIG};
    const u16* Bt = (z == 0) ? w1T : (z == 1) ? a1T : (z == 2) ? v1T : g1T;
    gemm_core(xmix + (size_t)sel[z] * BT * C_, C_, Bt, C_, hbuf + coff[z], 512, nreal[z], C_,
              blockIdx.y * 128, n0, epi[z], nullptr, nullptr);
}

// ---------------- weight transpose + bf16 convert ----------------
struct TDesc { const float* in; u16* out; int K; int N; };
struct TArgs { TDesc d[12]; };

__global__ void k_transpose(TArgs a) {
    TDesc dd = a.d[blockIdx.z];
    int k0 = blockIdx.x * 32, n0 = blockIdx.y * 32;
    if (k0 >= dd.K || n0 >= dd.N) return;
    __shared__ float tile[32][33];
    int tx = threadIdx.x & 31, ty = threadIdx.x >> 5;
#pragma unroll
    for (int i = 0; i < 32; i += 8)
        tile[ty + i][tx] = dd.in[(size_t)(k0 + ty + i) * dd.N + (n0 + tx)];
    __syncthreads();
#pragma unroll
    for (int i = 0; i < 32; i += 8)
        dd.out[(size_t)(n0 + ty + i) * dd.K + (k0 + tx)] = f2bf(tile[tx][ty + i]);
}

// ---------------- token-shift mixing ----------------
__global__ void k_mix(const float* __restrict__ x, const float* cr, const float* cw, const float* ck,
                      const float* cv, const float* ca, const float* cg, u16* __restrict__ xmix) {
    int idx = blockIdx.x * 256 + threadIdx.x;
    int c = idx & (C_ - 1);
    int bt = idx >> 11;
    int t = bt & (T_ - 1);
    float xv = x[idx];
    float xp = (t == 0) ? 0.f : x[idx - C_];
    float dx = xp - xv;
    const size_t S = (size_t)BT * C_;
    xmix[0 * S + idx] = f2bf(xv + dx * cr[c]);
    xmix[1 * S + idx] = f2bf(xv + dx * cw[c]);
    xmix[2 * S + idx] = f2bf(xv + dx * ck[c]);
    xmix[3 * S + idx] = f2bf(xv + dx * cv[c]);
    xmix[4 * S + idx] = f2bf(xv + dx * ca[c]);
    xmix[5 * S + idx] = f2bf(xv + dx * cg[c]);
}

// ---------------- head prep: kk normalize + k modulation ----------------
__global__ void k_headprep(u16* __restrict__ kb, const u16* __restrict__ ab,
                           const float* __restrict__ k_k, const float* __restrict__ k_a,
                           u16* __restrict__ kkb) {
    int g = blockIdx.x * 4 + (threadIdx.x >> 6);
    int lane = threadIdx.x & 63;
    size_t ix = (size_t)g * 64 + lane;
    int c = (g & (H_ - 1)) * 64 + lane;
    float kraw = bf2f(kb[ix]);
    float av = bf2f(ab[ix]);
    float kkv = kraw * k_k[c];
    float ss = kkv * kkv;
#pragma unroll
    for (int m = 32; m >= 1; m >>= 1) ss += __shfl_xor(ss, m, 64);
    float inv = 1.f / fmaxf(sqrtf(ss), 1e-12f);
    kkb[ix] = f2bf(kkv * inv);
    kb[ix] = f2bf(kraw * (1.f + (av - 1.f) * k_a[c]));
}

// ================= chunked WKV7 scan =================
// Per (b,h,chunk) unit u: time-major [t][n] arrays of 64x64.
//   cum[t][n] = prod_{s<=t} w[s][n] (fp32)
//   ahat[t] = cum[t-1] * (-kk_t)      bhat[s] = (kk_s*iclr_s)/cum[s]
//   khat[s] = k_s/cum[s]              rhat[t] = cum[t]*r_t
//   U[s][t] = bhat_s . ahat_t (s<t)   MinvT = ((I-U)^{-1})^T
//   PB[t][s] = bhat_s . rhat_t (s<=t) PK[t][s] = khat_s . rhat_t (s<=t)
//   Qt[t][s] = khat_s . ahat_t (s<t)  VQ[v][t] = sum_s Vt[v][s] Qt[t][s]
//   Btil[k][s] = cumL[k]*bhat_s[k]    Ktil[k][s] = cumL[k]*khat_s[k]
// Sequential phase per chunk:
//   RHS = S Ahat^T + VQ ; SA = RHS MinvT^T ; Y = Rhat S^T + PB SA^T + PK Vt^T
//   S' = S*cumL + SA Btil^T + Vt Ktil^T   (all in A[M,K] x B[N,K] gemm form)

// ---- block-level 64x64x64 gemm helper (4 waves, each 32x32) ----
DI bf16x8 frag64(const u16* p, int row, int ks, int lane) {
    return *(const bf16x8*)&p[(row + (lane & 15)) * 64 + ks * 32 + (lane >> 4) * 8];
}

DI void g64(const u16* lA, const u16* lB, f32x4 acc[2][2], int m0, int n0, int lane) {
#pragma unroll
    for (int ks = 0; ks < 2; ks++) {
        bf16x8 a0 = frag64(lA, m0, ks, lane);
        bf16x8 a1 = frag64(lA, m0 + 16, ks, lane);
        bf16x8 b0 = frag64(lB, n0, ks, lane);
        bf16x8 b1 = frag64(lB, n0 + 16, ks, lane);
        acc[0][0] = __builtin_amdgcn_mfma_f32_16x16x32_bf16(a0, b0, acc[0][0], 0, 0, 0);
        acc[0][1] = __builtin_amdgcn_mfma_f32_16x16x32_bf16(a0, b1, acc[0][1], 0, 0, 0);
        acc[1][0] = __builtin_amdgcn_mfma_f32_16x16x32_bf16(a1, b0, acc[1][0], 0, 0, 0);
        acc[1][1] = __builtin_amdgcn_mfma_f32_16x16x32_bf16(a1, b1, acc[1][1], 0, 0, 0);
    }
}

DI void stage8k(const u16* g, u16* l, int tid) {   // 4096 u16 = 8KB
    gload16(g + tid * 8, l + tid * 8);
    gload16(g + 2048 + tid * 8, l + 2048 + tid * 8);
}
DI void stage16k(const float* g, float* l, int tid) {  // 4096 f32 = 16KB
#pragma unroll
    for (int r = 0; r < 4; r++) gload16(g + r * 1024 + tid * 4, l + r * 1024 + tid * 4);
}

// ---- A1: cumprod + hat vectors + transposed copies ----
__global__ __launch_bounds__(256, 1) void k_prepA(
    const float* __restrict__ wdec, const u16* __restrict__ kkb, const u16* __restrict__ asig,
    const u16* __restrict__ kb, const u16* __restrict__ rb, const u16* __restrict__ vb,
    u16* __restrict__ Ahat, u16* __restrict__ Bhat, u16* __restrict__ Khat, u16* __restrict__ Rhat,
    u16* __restrict__ Vt, u16* __restrict__ Btil, u16* __restrict__ Ktil, float* __restrict__ cumLg) {
    __shared__ u16 stg[4][3][64 * 66];
    int tid = threadIdx.x, wv = tid >> 6, lane = tid & 63;
    int unit = blockIdx.x * 4 + wv;
    int c = unit & 15, bh = unit >> 4, h = bh & 31, b = bh >> 5;
    size_t ub = (size_t)unit * 4096;
    u16* sB = stg[wv][0]; u16* sK = stg[wv][1]; u16* sV = stg[wv][2];
    float cum = 1.f;
#pragma unroll 4
    for (int t = 0; t < 64; t++) {
        size_t gi = (((size_t)b * 1024 + c * 64 + t) * 32 + h) * 64 + lane;
        float w  = wdec[gi];
        float kk = bf2f(kkb[gi]), ic = bf2f(asig[gi]), km = bf2f(kb[gi]);
        float r  = bf2f(rb[gi]),  v  = bf2f(vb[gi]);
        float cp = cum; cum = cum * w;
        float inv = 1.f / cum;
        Ahat[ub + t * 64 + lane] = f2bf(-kk * cp);
        Rhat[ub + t * 64 + lane] = f2bf(r * cum);
        u16 bh_ = f2bf(kk * ic * inv), kh_ = f2bf(km * inv);
        Bhat[ub + t * 64 + lane] = bh_;
        Khat[ub + t * 64 + lane] = kh_;
        sB[t * 66 + lane] = bh_;
        sK[t * 66 + lane] = kh_;
        sV[t * 66 + lane] = f2bf(v);
    }
    cumLg[(size_t)unit * 64 + lane] = cum;
    // transposed writes: out row n = lane, 64 u16 = 128B per row
    union U64x { u16 h[64]; uint4 q[8]; };
    {
        U64x tm;
#pragma unroll
        for (int t = 0; t < 64; t++) tm.h[t] = f2bf(cum * bf2f(sB[t * 66 + lane]));
        uint4* p = (uint4*)(Btil + ub + lane * 64);
#pragma unroll
        for (int i = 0; i < 8; i++) p[i] = tm.q[i];
    }
    {
        U64x tm;
#pragma unroll
        for (int t = 0; t < 64; t++) tm.h[t] = f2bf(cum * bf2f(sK[t * 66 + lane]));
        uint4* p = (uint4*)(Ktil + ub + lane * 64);
#pragma unroll
        for (int i = 0; i < 8; i++) p[i] = tm.q[i];
    }
    {
        U64x tm;
#pragma unroll
        for (int t = 0; t < 64; t++) tm.h[t] = sV[t * 66 + lane];
        uint4* p = (uint4*)(Vt + ub + lane * 64);
#pragma unroll
        for (int i = 0; i < 8; i++) p[i] = tm.q[i];
    }
}

// ---- A2: PB / PK ----
__global__ __launch_bounds__(256, 1) void k_pbpk(const u16* __restrict__ Rhat, const u16* __restrict__ Bhat,
                                                 const u16* __restrict__ Khat, u16* __restrict__ PB,
                                                 u16* __restrict__ PK) {
    __shared__ u16 sA[4096], sB[4096];
    int tid = threadIdx.x, wv = tid >> 6, lane = tid & 63;
    int z = blockIdx.y;
    size_t ub = (size_t)blockIdx.x * 4096;
    stage8k(Rhat + ub, sA, tid);
    stage8k((z ? Khat : Bhat) + ub, sB, tid);
    __syncthreads();
    f32x4 acc[2][2] = {};
    int m0 = (wv >> 1) * 32, n0 = (wv & 1) * 32;
    g64(sA, sB, acc, m0, n0, lane);     // C[t][s]
    u16* Out = (z ? PK : PB);
#pragma unroll
    for (int mi = 0; mi < 2; mi++)
#pragma unroll
        for (int ni = 0; ni < 2; ni++)
#pragma unroll
            for (int rg = 0; rg < 4; rg++) {
                int m = m0 + mi * 16 + (lane >> 4) * 4 + rg;   // t
                int n = n0 + ni * 16 + (lane & 15);            // s
                Out[ub + m * 64 + n] = f2bf((n <= m) ? acc[mi][ni][rg] : 0.f);
            }
}

// ---- A3: U + triangular inverse (fp32) -> MinvT (bf16) ----
__global__ __launch_bounds__(256, 1) void k_minv(const u16* __restrict__ Bhat, const u16* __restrict__ Ahat,
                                                 u16* __restrict__ MinvT) {
    __shared__ u16 sA[4096], sB[4096];
    __shared__ float U[64 * 65];
    int tid = threadIdx.x, wv = tid >> 6, lane = tid & 63;
    size_t ub = (size_t)blockIdx.x * 4096;
    stage8k(Bhat + ub, sB, tid);
    stage8k(Ahat + ub, sA, tid);
    __syncthreads();
    f32x4 acc[2][2] = {};
    int m0 = (wv >> 1) * 32, n0 = (wv & 1) * 32;
    g64(sB, sA, acc, m0, n0, lane);     // C[s][t] = bhat_s . ahat_t
#pragma unroll
    for (int mi = 0; mi < 2; mi++)
#pragma unroll
        for (int ni = 0; ni < 2; ni++)
#pragma unroll
            for (int rg = 0; rg < 4; rg++) {
                int m = m0 + mi * 16 + (lane >> 4) * 4 + rg;   // s
                int n = n0 + ni * 16 + (lane & 15);            // t
                U[m * 65 + n] = (m < n) ? acc[mi][ni][rg] : 0.f;
            }
    __syncthreads();
    if (wv == 0) {
        // in-place: row s of U becomes row s of X = (I-U)^{-1}
        U[63 * 65 + lane] = (lane == 63) ? 1.f : 0.f;
        for (int s = 62; s >= 0; s--) {
            float a0 = 0.f, a1 = 0.f;
            int u = s + 1;
            for (; u + 1 < 64; u += 2) {
                a0 += U[s * 65 + u] * U[u * 65 + lane];
                a1 += U[s * 65 + u + 1] * U[(u + 1) * 65 + lane];
            }
            for (; u < 64; u++) a0 += U[s * 65 + u] * U[u * 65 + lane];
            float x = a0 + a1 + ((lane == s) ? 1.f : 0.f);
            U[s * 65 + lane] = x;
        }
        // MinvT[t=lane][s] = X[s][lane]
        union U64x { u16 h[64]; uint4 q[8]; } tm;
#pragma unroll
        for (int s = 0; s < 64; s++) tm.h[s] = f2bf(U[s * 65 + lane]);
        uint4* p = (uint4*)(MinvT + ub + lane * 64);
#pragma unroll
        for (int i = 0; i < 8; i++) p[i] = tm.q[i];
    }
}

// ---- A4: Qt (masked, LDS) + VQ = Vt x Qt^T ----
__global__ __launch_bounds__(256, 1) void k_vq(const u16* __restrict__ Ahat, const u16* __restrict__ Khat,
                                               const u16* __restrict__ Vt, float* __restrict__ VQ) {
    __shared__ u16 sA[4096], sK[4096], sV[4096], sQt[4096];
    int tid = threadIdx.x, wv = tid >> 6, lane = tid & 63;
    size_t ub = (size_t)blockIdx.x * 4096;
    stage8k(Ahat + ub, sA, tid);
    stage8k(Khat + ub, sK, tid);
    stage8k(Vt + ub, sV, tid);
    __syncthreads();
    int m0 = (wv >> 1) * 32, n0 = (wv & 1) * 32;
    {
        f32x4 acc[2][2] = {};
        g64(sA, sK, acc, m0, n0, lane);   // C[t][s] = khat_s . ahat_t
#pragma unroll
        for (int mi = 0; mi < 2; mi++)
#pragma unroll
            for (int ni = 0; ni < 2; ni++)
#pragma unroll
                for (int rg = 0; rg < 4; rg++) {
                    int m = m0 + mi * 16 + (lane >> 4) * 4 + rg;   // t
                    int n = n0 + ni * 16 + (lane & 15);            // s
                    sQt[m * 64 + n] = f2bf((n < m) ? acc[mi][ni][rg] : 0.f);
                }
    }
    __syncthreads();
    {
        f32x4 acc[2][2] = {};
        g64(sV, sQt, acc, m0, n0, lane);  // C[v][t] = sum_s Vt[v][s] Qt[t][s]
#pragma unroll
        for (int mi = 0; mi < 2; mi++)
#pragma unroll
            for (int ni = 0; ni < 2; ni++)
#pragma unroll
                for (int rg = 0; rg < 4; rg++) {
                    int m = m0 + mi * 16 + (lane >> 4) * 4 + rg;   // v
                    int n = n0 + ni * 16 + (lane & 15);            // t
                    VQ[ub + m * 64 + n] = acc[mi][ni][rg];
                }
    }
}

// ---- B: sequential chunk recurrence ----
__global__ __launch_bounds__(256, 1) void k_scanB(
    const u16* __restrict__ Ahat, const u16* __restrict__ MinvT, const u16* __restrict__ Rhat,
    const u16* __restrict__ PB, const u16* __restrict__ PK, const u16* __restrict__ Vt,
    const u16* __restrict__ Btil, const u16* __restrict__ Ktil,
    const float* __restrict__ VQ, const float* __restrict__ cumLg, u16* __restrict__ yout) {
    __shared__ u16 sS[4096];
    __shared__ float sSf[4096];
    __shared__ u16 sAhat[4096], sMinvT[4096], sRhat[4096], sPB[4096], sPK[4096],
                   sVt[4096], sBtil[4096], sKtil[4096], sRHS[4096], sSA[4096];
    __shared__ float sVQ[4096];
    __shared__ float sCumL[64];

    int tid = threadIdx.x, wv = tid >> 6, lane = tid & 63;
    int bh = blockIdx.x, h = bh & 31, b = bh >> 5;
    int m0 = (wv >> 1) * 32, n0 = (wv & 1) * 32;

    for (int i = tid; i < 4096; i += 256) { sSf[i] = 0.f; sS[i] = 0; }
    __syncthreads();

    for (int c = 0; c < NC; c++) {
        size_t ub = ((size_t)bh * NC + c) * 4096;
        stage8k(Ahat + ub, sAhat, tid);
        stage8k(MinvT + ub, sMinvT, tid);
        stage8k(Rhat + ub, sRhat, tid);
        stage8k(PB + ub, sPB, tid);
        stage8k(PK + ub, sPK, tid);
        stage8k(Vt + ub, sVt, tid);
        stage8k(Btil + ub, sBtil, tid);
        stage8k(Ktil + ub, sKtil, tid);
        stage16k(VQ + ub, sVQ, tid);
        if (tid < 16) gload16(cumLg + ((size_t)bh * NC + c) * 64 + tid * 4, sCumL + tid * 4);
        __syncthreads();

        // g1: RHS[v][t] = VQ + sum_k S[v][k] Ahat[t][k]
        {
            f32x4 acc[2][2];
#pragma unroll
            for (int mi = 0; mi < 2; mi++)
#pragma unroll
                for (int ni = 0; ni < 2; ni++)
#pragma unroll
                    for (int rg = 0; rg < 4; rg++) {
                        int m = m0 + mi * 16 + (lane >> 4) * 4 + rg;
                        int n = n0 + ni * 16 + (lane & 15);
                        acc[mi][ni][rg] = sVQ[m * 64 + n];
                    }
            g64(sS, sAhat, acc, m0, n0, lane);
#pragma unroll
            for (int mi = 0; mi < 2; mi++)
#pragma unroll
                for (int ni = 0; ni < 2; ni++)
#pragma unroll
                    for (int rg = 0; rg < 4; rg++) {
                        int m = m0 + mi * 16 + (lane >> 4) * 4 + rg;
                        int n = n0 + ni * 16 + (lane & 15);
                        sRHS[m * 64 + n] = f2bf(acc[mi][ni][rg]);
                    }
        }
        __syncthreads();
        // g2: SA[v][t] = sum_s RHS[v][s] Minv[s][t]
        {
            f32x4 acc[2][2] = {};
            g64(sRHS, sMinvT, acc, m0, n0, lane);
#pragma unroll
            for (int mi = 0; mi < 2; mi++)
#pragma unroll
                for (int ni = 0; ni < 2; ni++)
#pragma unroll
                    for (int rg = 0; rg < 4; rg++) {
                        int m = m0 + mi * 16 + (lane >> 4) * 4 + rg;
                        int n = n0 + ni * 16 + (lane & 15);
                        sSA[m * 64 + n] = f2bf(acc[mi][ni][rg]);
                    }
        }
        __syncthreads();
        // g3: Y[t][v] = Rhat x S + PB x SA + PK x Vt
        {
            f32x4 acc[2][2] = {};
            g64(sRhat, sS, acc, m0, n0, lane);
            g64(sPB, sSA, acc, m0, n0, lane);
            g64(sPK, sVt, acc, m0, n0, lane);
#pragma unroll
            for (int mi = 0; mi < 2; mi++)
#pragma unroll
                for (int ni = 0; ni < 2; ni++)
#pragma unroll
                    for (int rg = 0; rg < 4; rg++) {
                        int m = m0 + mi * 16 + (lane >> 4) * 4 + rg;   // t local
                        int n = n0 + ni * 16 + (lane & 15);            // v
                        size_t gi = (((size_t)b * 1024 + c * 64 + m) * 32 + h) * 64 + n;
                        yout[gi] = f2bf(acc[mi][ni][rg]);
                    }
        }
        __syncthreads();
        // g4: S'[v][k] = S*cumL[k] + SA x Btil + Vt x Ktil
        {
            f32x4 acc[2][2] = {};
            g64(sSA, sBtil, acc, m0, n0, lane);
            g64(sVt, sKtil, acc, m0, n0, lane);
#pragma unroll
            for (int mi = 0; mi < 2; mi++)
#pragma unroll
                for (int ni = 0; ni < 2; ni++)
#pragma unroll
                    for (int rg = 0; rg < 4; rg++) {
                        int m = m0 + mi * 16 + (lane >> 4) * 4 + rg;   // v
                        int n = n0 + ni * 16 + (lane & 15);            // k
                        float s_new = acc[mi][ni][rg] + sSf[m * 64 + n] * sCumL[n];
                        sSf[m * 64 + n] = s_new;
                        sS[m * 64 + n] = f2bf(s_new);
                    }
        }
        __syncthreads();
    }
}

// ---------------- GroupNorm + bonus + gate ----------------
__global__ void k_gn(const u16* __restrict__ y, const u16* __restrict__ rb, const u16* __restrict__ kb,
                     const u16* __restrict__ vb, const u16* __restrict__ gb,
                     const float* __restrict__ gn_w, const float* __restrict__ gn_b,
                     const float* __restrict__ r_k, u16* __restrict__ yg) {
    int g = blockIdx.x * 4 + (threadIdx.x >> 6);
    int lane = threadIdx.x & 63;
    size_t ix = (size_t)g * 64 + lane;
    int c = (g & (H_ - 1)) * 64 + lane;
    float yv = bf2f(y[ix]);
    float rv = bf2f(rb[ix]), kv = bf2f(kb[ix]);
    float m1 = yv, m2 = yv * yv, s = rv * kv * r_k[c];
#pragma unroll
    for (int m = 32; m >= 1; m >>= 1) {
        m1 += __shfl_xor(m1, m, 64);
        m2 += __shfl_xor(m2, m, 64);
        s  += __shfl_xor(s, m, 64);
    }
    m1 *= (1.f / 64.f);
    m2 *= (1.f / 64.f);
    float var = m2 - m1 * m1;
    float xn = (yv - m1) * rsqrtf(var + GN_EPS_C);
    xn = xn * gn_w[c] + gn_b[c];
    float out = (xn + s * bf2f(vb[ix])) * bf2f(gb[ix]);
    yg[ix] = f2bf(out);
}

// ---------------- launcher ----------------
extern "C" void kernel_launch(void* const* d_in, const int* in_sizes, int n_in,
                              void* d_out, int out_size, void* d_ws, size_t ws_size,
                              hipStream_t stream) {
    const float* x      = (const float*)d_in[0];
    const float* vfirst = (const float*)d_in[1];
    const float* x_r = (const float*)d_in[2];
    const float* x_w = (const float*)d_in[3];
    const float* x_k = (const float*)d_in[4];
    const float* x_v = (const float*)d_in[5];
    const float* x_a = (const float*)d_in[6];
    const float* x_g = (const float*)d_in[7];
    const float* w0 = (const float*)d_in[8];
    const float* w1 = (const float*)d_in[9];
    const float* w2 = (const float*)d_in[10];
    const float* a0 = (const float*)d_in[11];
    const float* a1 = (const float*)d_in[12];
    const float* a2 = (const float*)d_in[13];
    const float* v0 = (const float*)d_in[14];
    const float* v1 = (const float*)d_in[15];
    const float* v2 = (const float*)d_in[16];
    const float* g1 = (const float*)d_in[17];
    const float* g2 = (const float*)d_in[18];
    const float* k_k = (const float*)d_in[19];
    const float* k_a = (const float*)d_in[20];
    const float* r_k = (const float*)d_in[21];
    const float* W_r = (const float*)d_in[22];
    const float* W_k = (const float*)d_in[23];
    const float* W_v = (const float*)d_in[24];
    const float* W_o = (const float*)d_in[25];
    const float* gn_w = (const float*)d_in[26];
    const float* gn_b = (const float*)d_in[27];
    (void)in_sizes; (void)n_in; (void)out_size; (void)ws_size;

    char* wsp = (char*)d_ws;
    size_t off = 0;
    auto alloc = [&](size_t bytes) -> char* {
        char* p = wsp + off;
        off += (bytes + 255) & ~(size_t)255;
        return p;
    };
    const size_t MAT = (size_t)BT * C_;  // 4M elements

    u16* WrT = (u16*)alloc(MAT * 2);
    u16* WkT = (u16*)alloc(MAT * 2);
    u16* WvT = (u16*)alloc(MAT * 2);
    u16* WoT = (u16*)alloc(MAT * 2);
    u16* w1T = (u16*)alloc((size_t)128 * 2048 * 2);
    u16* a1T = (u16*)alloc((size_t)128 * 2048 * 2);
    u16* v1T = (u16*)alloc((size_t)128 * 2048 * 2);
    u16* g1T = (u16*)alloc((size_t)256 * 2048 * 2);
    u16* w2T = (u16*)alloc((size_t)2048 * 96 * 2);
    u16* a2T = (u16*)alloc((size_t)2048 * 96 * 2);
    u16* v2T = (u16*)alloc((size_t)2048 * 64 * 2);
    u16* g2T = (u16*)alloc((size_t)2048 * 256 * 2);
    char* xmixR = alloc(6 * MAT * 2);          // 48MB; aliased by scan scratch later
    u16* xmix = (u16*)xmixR;
    u16* hbuf = (u16*)alloc((size_t)BT * 512 * 2);
    u16* rbuf = (u16*)alloc(MAT * 2);
    u16* kbuf = (u16*)alloc(MAT * 2);
    u16* vbuf = (u16*)alloc(MAT * 2);
    u16* kkbuf = (u16*)alloc(MAT * 2);
    u16* asig = (u16*)alloc(MAT * 2);
    float* wdec = (float*)alloc(MAT * 4);
    u16* gbuf = (u16*)alloc(MAT * 2);
    u16* ybuf = (u16*)alloc(MAT * 2);
    u16* ygbuf = (u16*)alloc(MAT * 2);
    // scan scratch (UNITS * 4096 elements each)
    const size_t UE = (size_t)UNITS * 4096;
    u16* Ahat = (u16*)alloc(UE * 2);
    u16* Khat = (u16*)alloc(UE * 2);
    u16* Rhat = (u16*)alloc(UE * 2);
    u16* Vt   = (u16*)alloc(UE * 2);
    u16* Btil = (u16*)alloc(UE * 2);
    u16* Ktil = (u16*)alloc(UE * 2);
    // aliases: Bhat over ygbuf (dead until k_gn); MinvT/PB/PK/VQ/cumL over xmix (dead after rkv/upproj)
    u16* Bhat  = ygbuf;
    u16* MinvT = (u16*)(xmixR);
    u16* PB    = (u16*)(xmixR + (size_t)8 * 1024 * 1024);
    u16* PK    = (u16*)(xmixR + (size_t)16 * 1024 * 1024);
    float* VQ  = (float*)(xmixR + (size_t)24 * 1024 * 1024);
    float* cumLg = (float*)(xmixR + (size_t)40 * 1024 * 1024);

    // 1) weight transposes
    TArgs ta;
    ta.d[0]  = {W_r, WrT, 2048, 2048};
    ta.d[1]  = {W_k, WkT, 2048, 2048};
    ta.d[2]  = {W_v, WvT, 2048, 2048};
    ta.d[3]  = {W_o, WoT, 2048, 2048};
    ta.d[4]  = {w1, w1T, 2048, 96};
    ta.d[5]  = {a1, a1T, 2048, 96};
    ta.d[6]  = {v1, v1T, 2048, 64};
    ta.d[7]  = {g1, g1T, 2048, 256};
    ta.d[8]  = {w2, w2T, 96, 2048};
    ta.d[9]  = {a2, a2T, 96, 2048};
    ta.d[10] = {v2, v2T, 64, 2048};
    ta.d[11] = {g2, g2T, 256, 2048};
    k_transpose<<<dim3(64, 64, 12), 256, 0, stream>>>(ta);

    // 2) token-shift mixes
    k_mix<<<dim3((unsigned)(MAT / 256)), 256, 0, stream>>>(x, x_r, x_w, x_k, x_v, x_a, x_g, xmix);

    // 3) LoRA up-projections
    k_upproj<<<dim3(2, 16, 4), 256, 0, stream>>>(xmix, w1T, a1T, v1T, g1T, hbuf);

    // 4) big GEMMs r/k/v
    k_gemm_rkv<<<dim3(16, 16, 3), 256, 0, stream>>>(xmix, WrT, WkT, WvT, rbuf, kbuf, vbuf);

    // 5) LoRA down-projections with fused epilogues
    k_gemm<<<dim3(16, 16), 256, 0, stream>>>(hbuf + 0, 512, w2T, 96, wdec, 2048, 2048, 96, EP_DECAY, w0, nullptr);
    k_gemm<<<dim3(16, 16), 256, 0, stream>>>(hbuf + 96, 512, a2T, 96, asig, 2048, 2048, 96, EP_ASIG, a0, nullptr);
    k_gemm<<<dim3(16, 16), 256, 0, stream>>>(hbuf + 192, 512, v2T, 64, vbuf, 2048, 2048, 64, EP_VMIX, v0, vfirst);
    k_gemm<<<dim3(16, 16), 256, 0, stream>>>(hbuf + 256, 512, g2T, 256, gbuf, 2048, 2048, 256, EP_BF16, nullptr, nullptr);

    // 6) head prep
    k_headprep<<<dim3(BT * H_ / 4), 256, 0, stream>>>(kbuf, asig, k_k, k_a, kkbuf);

    // 7) chunked scan: phase A (parallel over 1024 units)
    k_prepA<<<dim3(UNITS / 4), 256, 0, stream>>>(wdec, kkbuf, asig, kbuf, rbuf, vbuf,
                                                 Ahat, Bhat, Khat, Rhat, Vt, Btil, Ktil, cumLg);
    k_pbpk<<<dim3(UNITS, 2), 256, 0, stream>>>(Rhat, Bhat, Khat, PB, PK);
    k_minv<<<dim3(UNITS), 256, 0, stream>>>(Bhat, Ahat, MinvT);
    k_vq<<<dim3(UNITS), 256, 0, stream>>>(Ahat, Khat, Vt, VQ);
    // phase B (sequential over 16 chunks, 64 blocks)
    k_scanB<<<dim3(B_ * H_), 256, 0, stream>>>(Ahat, MinvT, Rhat, PB, PK, Vt, Btil, Ktil,
                                               VQ, cumLg, ybuf);

    // 8) GroupNorm + bonus + gate
    k_gn<<<dim3(BT * H_ / 4), 256, 0, stream>>>(ybuf, rbuf, kbuf, vbuf, gbuf, gn_w, gn_b, r_k, ygbuf);

    // 9) output projection
    k_gemm<<<dim3(16, 16), 256, 0, stream>>>(ygbuf, 2048, WoT, 2048, d_out, 2048, 2048, 2048, EP_F32, nullptr, nullptr);
}

// Round 3
// 698.746 us; speedup vs baseline: 1.8620x; 1.0502x over previous
//
#include <hip/hip_runtime.h>
#include <cstdint>
#include <cstddef>

#define DI __device__ __forceinline__

typedef unsigned short u16;

// ---------------- problem constants ----------------
constexpr int B_ = 2, T_ = 1024, C_ = 2048, H_ = 32, N_ = 64;
constexpr int BT = B_ * T_;            // 2048 rows
constexpr float GN_EPS_C = 64e-5f;     // N * 1e-5
constexpr int LCH = 64;                // scan chunk length
constexpr int NC = T_ / LCH;           // 16 chunks
constexpr int UNITS = B_ * H_ * NC;    // 1024 (b,h,chunk) units

// ---------------- small helpers ----------------
DI float bf2f(u16 h) {
    union { unsigned u; float f; } x; x.u = ((unsigned)h) << 16; return x.f;
}
DI u16 f2bf(float f) {
    union { float f; unsigned u; } x; x.f = f;
    unsigned r = (x.u + 0x7fffu + ((x.u >> 16) & 1u)) >> 16;
    return (u16)r;
}
DI float sigmoidf_(float x) { return 1.f / (1.f + __expf(-x)); }

typedef __attribute__((ext_vector_type(8))) __bf16 bf16x8;
typedef __attribute__((ext_vector_type(4))) float f32x4;

DI void gload16(const void* g, void* l) {
    __builtin_amdgcn_global_load_lds(
        (const __attribute__((address_space(1))) void*)g,
        (__attribute__((address_space(3))) void*)l,
        16, 0, 0);
}

// ---------------- epilogue ids ----------------
enum { EP_BF16 = 0, EP_F32 = 1, EP_TANH = 2, EP_SIG = 3, EP_DECAY = 4, EP_ASIG = 5, EP_VMIX = 6 };

// ---------------- generic 128x128x32 bf16 MFMA GEMM core (m97 recipe) ----------------
DI void gemm_core(const u16* __restrict__ A, int lda,
                  const u16* __restrict__ Bt, int ldb,
                  void* __restrict__ Out, int ldc,
                  int Nreal, int K, int m0, int n0, int epi,
                  const float* __restrict__ aux0, const float* __restrict__ aux1) {
    __shared__ u16 lA[128 * 32];
    __shared__ u16 lB[128 * 32];
    const int tid = threadIdx.x;
    const int lane = tid & 63;
    const int wv = tid >> 6;
    const int wr = wv >> 1, wc = wv & 1;
    const int r0 = tid >> 2;
    const int cc0 = (tid & 3) * 8;

    f32x4 acc[4][4];
#pragma unroll
    for (int i = 0; i < 4; i++)
#pragma unroll
        for (int j = 0; j < 4; j++) acc[i][j] = (f32x4){0.f, 0.f, 0.f, 0.f};

    const u16* Abase = A + (size_t)(m0 + r0) * lda + cc0;
    const u16* Bbase = Bt + (size_t)(n0 + r0) * ldb + cc0;
    u16* lA0 = &lA[r0 * 32 + cc0];
    u16* lA1 = &lA[(r0 + 64) * 32 + cc0];
    u16* lB0 = &lB[r0 * 32 + cc0];
    u16* lB1 = &lB[(r0 + 64) * 32 + cc0];

    for (int k0 = 0; k0 < K; k0 += 32) {
        __syncthreads();
        gload16(Abase + k0, lA0);
        gload16(Abase + (size_t)64 * lda + k0, lA1);
        gload16(Bbase + k0, lB0);
        gload16(Bbase + (size_t)64 * ldb + k0, lB1);
        __syncthreads();
        bf16x8 af[4], bfr[4];
#pragma unroll
        for (int i = 0; i < 4; i++) {
            af[i]  = *(const bf16x8*)&lA[(wr * 64 + i * 16 + (lane & 15)) * 32 + (lane >> 4) * 8];
            bfr[i] = *(const bf16x8*)&lB[(wc * 64 + i * 16 + (lane & 15)) * 32 + (lane >> 4) * 8];
        }
#pragma unroll
        for (int mi = 0; mi < 4; mi++)
#pragma unroll
            for (int ni = 0; ni < 4; ni++)
                acc[mi][ni] = __builtin_amdgcn_mfma_f32_16x16x32_bf16(af[mi], bfr[ni], acc[mi][ni], 0, 0, 0);
    }

#pragma unroll
    for (int mi = 0; mi < 4; mi++) {
#pragma unroll
        for (int ni = 0; ni < 4; ni++) {
            int n = n0 + wc * 64 + ni * 16 + (lane & 15);
            if (n >= Nreal) continue;
#pragma unroll
            for (int rg = 0; rg < 4; rg++) {
                int m = m0 + wr * 64 + mi * 16 + (lane >> 4) * 4 + rg;
                size_t ix = (size_t)m * ldc + n;
                float f = acc[mi][ni][rg];
                switch (epi) {
                    case EP_BF16: ((u16*)Out)[ix] = f2bf(f); break;
                    case EP_F32:  ((float*)Out)[ix] = f; break;
                    case EP_TANH: ((u16*)Out)[ix] = f2bf(tanhf(f)); break;
                    case EP_SIG:  ((u16*)Out)[ix] = f2bf(sigmoidf_(f)); break;
                    case EP_DECAY: {
                        float z = -(aux0[n] + f);
                        float sp = (z > 15.f) ? z : log1pf(expf(z));
                        ((float*)Out)[ix] = expf(-expf(-0.5f - sp));
                    } break;
                    case EP_ASIG: ((u16*)Out)[ix] = f2bf(sigmoidf_(aux0[n] + f)); break;
                    case EP_VMIX: {
                        float vs = sigmoidf_(aux0[n] + f);
                        float old = bf2f(((u16*)Out)[ix]);
                        float vf = aux1[ix];
                        ((u16*)Out)[ix] = f2bf(old + (vf - old) * vs);
                    } break;
                }
            }
        }
    }
}

// ---- fused big GEMMs: z 0..2 = r/k/v projections; z 3..6 = LoRA up-projections ----
__global__ __launch_bounds__(256, 1) void k_gemm7(const u16* xmix, const u16* WrT, const u16* WkT,
                                                  const u16* WvT, const u16* w1T, const u16* a1T,
                                                  const u16* v1T, const u16* g1T,
                                                  u16* rb, u16* kb, u16* vb, u16* hbuf) {
    int z = blockIdx.z;
    if (z < 3) {
        const int sel[3] = {0, 2, 3};  // xr, xk, xv
        const u16* A = xmix + (size_t)sel[z] * BT * C_;
        const u16* Bt = (z == 0) ? WrT : (z == 1) ? WkT : WvT;
        u16* Out = (z == 0) ? rb : (z == 1) ? kb : vb;
        gemm_core(A, C_, Bt, C_, Out, C_, C_, C_, blockIdx.y * 128, blockIdx.x * 128, EP_BF16, nullptr, nullptr);
    } else {
        int zz = z - 3;
        const int xlim[4]  = {1, 1, 1, 2};
        if ((int)blockIdx.x >= xlim[zz]) return;
        const int sel[4]   = {1, 4, 3, 5};        // xw, xa, xv, xg
        const int nreal[4] = {96, 96, 64, 256};
        const int coff[4]  = {0, 96, 192, 256};
        const int epi[4]   = {EP_TANH, EP_BF16, EP_BF16, EP_SIG};
        const u16* Bt = (zz == 0) ? w1T : (zz == 1) ? a1T : (zz == 2) ? v1T : g1T;
        gemm_core(xmix + (size_t)sel[zz] * BT * C_, C_, Bt, C_, hbuf + coff[zz], 512, nreal[zz], C_,
                  blockIdx.y * 128, blockIdx.x * 128, epi[zz], nullptr, nullptr);
    }
}

// ---- fused LoRA down-projections (z 0..3) ----
__global__ __launch_bounds__(256, 1) void k_down4(const u16* hbuf, const u16* w2T, const u16* a2T,
                                                  const u16* v2T, const u16* g2T,
                                                  float* wdec, u16* asig, u16* vbuf, u16* gbuf,
                                                  const float* w0, const float* a0, const float* v0,
                                                  const float* vfirst) {
    int z = blockIdx.z;
    const int Ks[4]   = {96, 96, 64, 256};
    const int coff[4] = {0, 96, 192, 256};
    const int epi[4]  = {EP_DECAY, EP_ASIG, EP_VMIX, EP_BF16};
    const u16* Bt = (z == 0) ? w2T : (z == 1) ? a2T : (z == 2) ? v2T : g2T;
    void* Out = (z == 0) ? (void*)wdec : (z == 1) ? (void*)asig : (z == 2) ? (void*)vbuf : (void*)gbuf;
    const float* aux0 = (z == 0) ? w0 : (z == 1) ? a0 : (z == 2) ? v0 : nullptr;
    const float* aux1 = (z == 2) ? vfirst : nullptr;
    gemm_core(hbuf + coff[z], 512, Bt, Ks[z], Out, 2048, 2048, Ks[z],
              blockIdx.y * 128, blockIdx.x * 128, epi[z], aux0, aux1);
}

// ---------------- weight transpose + bf16 convert ----------------
struct TDesc { const float* in; u16* out; int K; int N; };
struct TArgs { TDesc d[12]; };

__global__ void k_transpose(TArgs a) {
    TDesc dd = a.d[blockIdx.z];
    int k0 = blockIdx.x * 32, n0 = blockIdx.y * 32;
    if (k0 >= dd.K || n0 >= dd.N) return;
    __shared__ float tile[32][33];
    int tx = threadIdx.x & 31, ty = threadIdx.x >> 5;
#pragma unroll
    for (int i = 0; i < 32; i += 8)
        tile[ty + i][tx] = dd.in[(size_t)(k0 + ty + i) * dd.N + (n0 + tx)];
    __syncthreads();
#pragma unroll
    for (int i = 0; i < 32; i += 8)
        dd.out[(size_t)(n0 + ty + i) * dd.K + (k0 + tx)] = f2bf(tile[tx][ty + i]);
}

// ---------------- token-shift mixing (x4 vectorized) ----------------
__global__ void k_mix(const float* __restrict__ x, const float* cr, const float* cw, const float* ck,
                      const float* cv, const float* ca, const float* cg, u16* __restrict__ xmix) {
    int idx = blockIdx.x * 256 + threadIdx.x;
    int base = idx * 4;
    int c4 = base & (C_ - 1);
    int bt = base >> 11;
    int t = bt & (T_ - 1);
    float4 xv = *(const float4*)(x + base);
    float4 xp = (t == 0) ? (float4){0.f, 0.f, 0.f, 0.f} : *(const float4*)(x + base - C_);
    float4 dx = {xp.x - xv.x, xp.y - xv.y, xp.z - xv.z, xp.w - xv.w};
    const size_t S = (size_t)BT * C_;
    const float* cs[6] = {cr, cw, ck, cv, ca, cg};
#pragma unroll
    for (int j = 0; j < 6; j++) {
        float4 cc = *(const float4*)(cs[j] + c4);
        ushort4 o;
        o.x = f2bf(xv.x + dx.x * cc.x);
        o.y = f2bf(xv.y + dx.y * cc.y);
        o.z = f2bf(xv.z + dx.z * cc.z);
        o.w = f2bf(xv.w + dx.w * cc.w);
        *(ushort4*)(xmix + j * S + base) = o;
    }
}

// ---------------- head prep: kk normalize + k modulation ----------------
__global__ void k_headprep(u16* __restrict__ kb, const u16* __restrict__ ab,
                           const float* __restrict__ k_k, const float* __restrict__ k_a,
                           u16* __restrict__ kkb) {
    int g = blockIdx.x * 4 + (threadIdx.x >> 6);
    int lane = threadIdx.x & 63;
    size_t ix = (size_t)g * 64 + lane;
    int c = (g & (H_ - 1)) * 64 + lane;
    float kraw = bf2f(kb[ix]);
    float av = bf2f(ab[ix]);
    float kkv = kraw * k_k[c];
    float ss = kkv * kkv;
#pragma unroll
    for (int m = 32; m >= 1; m >>= 1) ss += __shfl_xor(ss, m, 64);
    float inv = 1.f / fmaxf(sqrtf(ss), 1e-12f);
    kkb[ix] = f2bf(kkv * inv);
    kb[ix] = f2bf(kraw * (1.f + (av - 1.f) * k_a[c]));
}

// ================= chunked WKV7 scan =================
// Per (b,h,chunk) unit: time-major [t][n] 64x64 tiles.
//   cum[t][n] = prod_{s<=t} w ; ahat[t]=cum[t-1]*(-kk_t); bhat[s]=(kk_s*iclr_s)/cum[s]
//   khat[s]=k_s/cum[s]; rhat[t]=cum[t]*r_t
//   U[s][t]=bhat_s.ahat_t (s<t); X=(I-U)^{-1}
//   PB[t][s]=bhat_s.rhat_t (s<=t); PK[t][s]=khat_s.rhat_t (s<=t)
//   Qt[t][s]=khat_s.ahat_t (s<t); VQ = Vt x Qt^T
//   G1T[t][k] = sum_s Ahat[s][k] X[s][t];  VQM = VQ x X
// Sequential per chunk: SA = S x G1T-form + VQM ; S' = (S + SA.bhat + Vt.khat) * cumL[k]
// Parallel Y: Y = Rhat x Sin^T + PB x SA^T + PK x Vt^T

DI bf16x8 frag64(const u16* p, int row, int ks, int lane) {
    return *(const bf16x8*)&p[(row + (lane & 15)) * 64 + ks * 32 + (lane >> 4) * 8];
}

DI void g64(const u16* lA, const u16* lB, f32x4 acc[2][2], int m0, int n0, int lane) {
#pragma unroll
    for (int ks = 0; ks < 2; ks++) {
        bf16x8 a0 = frag64(lA, m0, ks, lane);
        bf16x8 a1 = frag64(lA, m0 + 16, ks, lane);
        bf16x8 b0 = frag64(lB, n0, ks, lane);
        bf16x8 b1 = frag64(lB, n0 + 16, ks, lane);
        acc[0][0] = __builtin_amdgcn_mfma_f32_16x16x32_bf16(a0, b0, acc[0][0], 0, 0, 0);
        acc[0][1] = __builtin_amdgcn_mfma_f32_16x16x32_bf16(a0, b1, acc[0][1], 0, 0, 0);
        acc[1][0] = __builtin_amdgcn_mfma_f32_16x16x32_bf16(a1, b0, acc[1][0], 0, 0, 0);
        acc[1][1] = __builtin_amdgcn_mfma_f32_16x16x32_bf16(a1, b1, acc[1][1], 0, 0, 0);
    }
}

DI void stage8k(const u16* g, u16* l, int tid) {   // 4096 u16 = 8KB
    gload16(g + tid * 8, l + tid * 8);
    gload16(g + 2048 + tid * 8, l + 2048 + tid * 8);
}

// ---- A1: cumprod + hat vectors + transposed copies ----
__global__ __launch_bounds__(256, 1) void k_prepA(
    const float* __restrict__ wdec, const u16* __restrict__ kkb, const u16* __restrict__ asig,
    const u16* __restrict__ kb, const u16* __restrict__ rb, const u16* __restrict__ vb,
    u16* __restrict__ Ahat, u16* __restrict__ Bhat, u16* __restrict__ Khat, u16* __restrict__ Rhat,
    u16* __restrict__ Vt, u16* __restrict__ BhatT, u16* __restrict__ KhatT, float* __restrict__ cumLg) {
    __shared__ u16 stg[4][3][64 * 66];
    int tid = threadIdx.x, wv = tid >> 6, lane = tid & 63;
    int unit = blockIdx.x * 4 + wv;
    int c = unit & 15, bh = unit >> 4, h = bh & 31, b = bh >> 5;
    size_t ub = (size_t)unit * 4096;
    u16* sB = stg[wv][0]; u16* sK = stg[wv][1]; u16* sV = stg[wv][2];
    float cum = 1.f;
#pragma unroll 4
    for (int t = 0; t < 64; t++) {
        size_t gi = (((size_t)b * 1024 + c * 64 + t) * 32 + h) * 64 + lane;
        float w  = wdec[gi];
        float kk = bf2f(kkb[gi]), ic = bf2f(asig[gi]), km = bf2f(kb[gi]);
        float r  = bf2f(rb[gi]),  v  = bf2f(vb[gi]);
        float cp = cum; cum = cum * w;
        float inv = 1.f / cum;
        Ahat[ub + t * 64 + lane] = f2bf(-kk * cp);
        Rhat[ub + t * 64 + lane] = f2bf(r * cum);
        u16 bh_ = f2bf(kk * ic * inv), kh_ = f2bf(km * inv);
        Bhat[ub + t * 64 + lane] = bh_;
        Khat[ub + t * 64 + lane] = kh_;
        sB[t * 66 + lane] = bh_;
        sK[t * 66 + lane] = kh_;
        sV[t * 66 + lane] = f2bf(v);
    }
    cumLg[(size_t)unit * 64 + lane] = cum;
    union U64x { u16 h[64]; uint4 q[8]; };
    {
        U64x tm;
#pragma unroll
        for (int t = 0; t < 64; t++) tm.h[t] = sB[t * 66 + lane];
        uint4* p = (uint4*)(BhatT + ub + lane * 64);
#pragma unroll
        for (int i = 0; i < 8; i++) p[i] = tm.q[i];
    }
    {
        U64x tm;
#pragma unroll
        for (int t = 0; t < 64; t++) tm.h[t] = sK[t * 66 + lane];
        uint4* p = (uint4*)(KhatT + ub + lane * 64);
#pragma unroll
        for (int i = 0; i < 8; i++) p[i] = tm.q[i];
    }
    {
        U64x tm;
#pragma unroll
        for (int t = 0; t < 64; t++) tm.h[t] = sV[t * 66 + lane];
        uint4* p = (uint4*)(Vt + ub + lane * 64);
#pragma unroll
        for (int i = 0; i < 8; i++) p[i] = tm.q[i];
    }
}

// ---- A2 fused: U -> blocked inversion -> PB/PK/Qt/VQ -> G1T/VQM ----
__global__ __launch_bounds__(256, 1) void k_chunkops(
    const u16* __restrict__ Ahat, const u16* __restrict__ Bhat, const u16* __restrict__ Khat,
    const u16* __restrict__ Rhat, const u16* __restrict__ Vt,
    u16* __restrict__ PB, u16* __restrict__ PK, u16* __restrict__ G1T, u16* __restrict__ VQM) {
    __shared__ u16 sA[4096], sB[4096], sK[4096], sR[4096], sV[4096], sQt[4096], sAT[4096];
    __shared__ float Uf[64 * 65];
    int tid = threadIdx.x, wv = tid >> 6, lane = tid & 63;
    size_t ub = (size_t)blockIdx.x * 4096;
    int m0 = (wv >> 1) * 32, n0 = (wv & 1) * 32;
    u16* sMt = sB;   // alias: sB dead after P2
    u16* sVQ = sR;   // alias: sR dead after P2

    stage8k(Ahat + ub, sA, tid);
    stage8k(Bhat + ub, sB, tid);
    stage8k(Khat + ub, sK, tid);
    stage8k(Rhat + ub, sR, tid);
    stage8k(Vt + ub, sV, tid);
    __syncthreads();

    // P1: U[s][t] (strict upper) + AhatT
    {
        f32x4 acc[2][2] = {};
        g64(sB, sA, acc, m0, n0, lane);
#pragma unroll
        for (int mi = 0; mi < 2; mi++)
#pragma unroll
            for (int ni = 0; ni < 2; ni++)
#pragma unroll
                for (int rg = 0; rg < 4; rg++) {
                    int m = m0 + mi * 16 + (lane >> 4) * 4 + rg;   // s
                    int n = n0 + ni * 16 + (lane & 15);            // t
                    Uf[m * 65 + n] = (m < n) ? acc[mi][ni][rg] : 0.f;
                }
#pragma unroll
        for (int i = 0; i < 16; i++) {
            int idx = tid * 16 + i;
            int k = idx >> 6, s = idx & 63;
            sAT[idx] = sA[s * 64 + k];
        }
    }
    __syncthreads();

    // P2: PB, PK (global) + Qt (LDS)
    {
        f32x4 a1[2][2] = {}, a2[2][2] = {}, a3[2][2] = {};
        g64(sR, sB, a1, m0, n0, lane);
        g64(sR, sK, a2, m0, n0, lane);
        g64(sA, sK, a3, m0, n0, lane);
#pragma unroll
        for (int mi = 0; mi < 2; mi++)
#pragma unroll
            for (int ni = 0; ni < 2; ni++)
#pragma unroll
                for (int rg = 0; rg < 4; rg++) {
                    int m = m0 + mi * 16 + (lane >> 4) * 4 + rg;
                    int n = n0 + ni * 16 + (lane & 15);
                    PB[ub + m * 64 + n] = f2bf((n <= m) ? a1[mi][ni][rg] : 0.f);
                    PK[ub + m * 64 + n] = f2bf((n <= m) ? a2[mi][ni][rg] : 0.f);
                    sQt[m * 64 + n] = f2bf((n < m) ? a3[mi][ni][rg] : 0.f);
                }
    }
    __syncthreads();

    // P3: blocked inversion of (I-U), in place in Uf. Blocks 16x16.
    // diag blocks (parallel across waves)
    if (lane < 16) {
        int s0 = wv * 16, t = lane;
        Uf[(s0 + 15) * 65 + (s0 + t)] = (t == 15) ? 1.f : 0.f;
        for (int s = 14; s >= 0; s--) {
            float acc = (t == s) ? 1.f : 0.f;
            for (int u = s + 1; u < 16; u++)
                acc += Uf[(s0 + s) * 65 + (s0 + u)] * Uf[(s0 + u) * 65 + (s0 + t)];
            Uf[(s0 + s) * 65 + (s0 + t)] = acc;
        }
    }
    __syncthreads();
    // off-diagonal columns j=1..3: X_ij = (sum_{p=i..j-1} X_ip U_pj) X_jj, waves parallel over i
    for (int j = 1; j <= 3; j++) {
        float Xn[4];
        int t = lane & 15, q = lane >> 4;
        bool act = (wv < j);
        if (act) {
            int i = wv;
            float Wreg[4];
#pragma unroll
            for (int ri = 0; ri < 4; ri++) {
                int r = q * 4 + ri;
                float w = 0.f;
                for (int p = i; p < j; p++)
#pragma unroll
                    for (int u = 0; u < 16; u++)
                        w += Uf[(i * 16 + r) * 65 + p * 16 + u] * Uf[(p * 16 + u) * 65 + j * 16 + t];
                Wreg[ri] = w;
            }
#pragma unroll
            for (int ri = 0; ri < 4; ri++) {
                float acc = 0.f;
#pragma unroll
                for (int u = 0; u < 16; u++)
                    acc += __shfl(Wreg[ri], (lane & 48) + u, 64) * Uf[(j * 16 + u) * 65 + (j * 16 + t)];
                Xn[ri] = acc;
            }
        }
        __syncthreads();
        if (act) {
#pragma unroll
            for (int ri = 0; ri < 4; ri++)
                Uf[(wv * 16 + q * 4 + ri) * 65 + j * 16 + t] = Xn[ri];
        }
        __syncthreads();
    }
    // sMt[t][s] = X[s][t] (bf16), over sB
#pragma unroll
    for (int i = 0; i < 16; i++) {
        int idx = tid * 16 + i;
        int t = idx >> 6, s = idx & 63;
        sMt[idx] = f2bf((s <= t) ? Uf[s * 65 + t] : 0.f);
    }
    __syncthreads();

    // P4: VQ = Vt x Qt^T -> sVQ (over sR)
    {
        f32x4 acc[2][2] = {};
        g64(sV, sQt, acc, m0, n0, lane);
#pragma unroll
        for (int mi = 0; mi < 2; mi++)
#pragma unroll
            for (int ni = 0; ni < 2; ni++)
#pragma unroll
                for (int rg = 0; rg < 4; rg++) {
                    int m = m0 + mi * 16 + (lane >> 4) * 4 + rg;
                    int n = n0 + ni * 16 + (lane & 15);
                    sVQ[m * 64 + n] = f2bf(acc[mi][ni][rg]);
                }
    }
    __syncthreads();

    // P5: VQM = VQ x X ; G1T[t][k] = sum_s X[s][t] Ahat[s][k]
    {
        f32x4 a1[2][2] = {}, a2[2][2] = {};
        g64(sVQ, sMt, a1, m0, n0, lane);
        g64(sMt, sAT, a2, m0, n0, lane);
#pragma unroll
        for (int mi = 0; mi < 2; mi++)
#pragma unroll
            for (int ni = 0; ni < 2; ni++)
#pragma unroll
                for (int rg = 0; rg < 4; rg++) {
                    int m = m0 + mi * 16 + (lane >> 4) * 4 + rg;
                    int n = n0 + ni * 16 + (lane & 15);
                    VQM[ub + m * 64 + n] = f2bf(a1[mi][ni][rg]);
                    G1T[ub + m * 64 + n] = f2bf(a2[mi][ni][rg]);
                }
    }
}

// ---- B: sequential chunk recurrence (SA + Sin only) ----
__global__ __launch_bounds__(256, 1) void k_scanBl(
    const u16* __restrict__ G1T, const u16* __restrict__ VQM, const u16* __restrict__ BhatT,
    const u16* __restrict__ KhatT, const u16* __restrict__ Vt, const float* __restrict__ cumLg,
    u16* __restrict__ SA, u16* __restrict__ Sin) {
    __shared__ u16 bG1[2][4096], bVQ[2][4096], bBh[2][4096], bKh[2][4096], bVt[2][4096];
    __shared__ u16 sSA[4096], sS[4096];
    __shared__ float sSf[4096];
    __shared__ float sCumL[2][64];

    int tid = threadIdx.x, wv = tid >> 6, lane = tid & 63;
    int bh = blockIdx.x;
    int m0 = (wv >> 1) * 32, n0 = (wv & 1) * 32;

    for (int i = tid; i < 4096; i += 256) { sSf[i] = 0.f; sS[i] = 0; }
    {   // Sin chunk 0 = zeros
        uint4 z = {0, 0, 0, 0};
        uint4* p = (uint4*)(Sin + (size_t)bh * NC * 4096);
        for (int i = tid; i < 512; i += 256) p[i] = z;
    }

    auto stage = [&](int c, int buf) {
        size_t ub = ((size_t)bh * NC + c) * 4096;
        stage8k(G1T + ub, bG1[buf], tid);
        stage8k(VQM + ub, bVQ[buf], tid);
        stage8k(BhatT + ub, bBh[buf], tid);
        stage8k(KhatT + ub, bKh[buf], tid);
        stage8k(Vt + ub, bVt[buf], tid);
        if (tid < 16) gload16(cumLg + ((size_t)bh * NC + c) * 64 + tid * 4, &sCumL[buf][tid * 4]);
    };

    stage(0, 0);
    for (int c = 0; c < NC; c++) {
        int cur = c & 1;
        __syncthreads();                  // B1: staged data + prev S' visible
        if (c + 1 < NC) stage(c + 1, 1 - cur);
        size_t ub = ((size_t)bh * NC + c) * 4096;

        // gSA: SA = S x G1T-form + VQM
        {
            f32x4 acc[2][2];
#pragma unroll
            for (int mi = 0; mi < 2; mi++)
#pragma unroll
                for (int ni = 0; ni < 2; ni++)
#pragma unroll
                    for (int rg = 0; rg < 4; rg++) {
                        int m = m0 + mi * 16 + (lane >> 4) * 4 + rg;
                        int n = n0 + ni * 16 + (lane & 15);
                        acc[mi][ni][rg] = bf2f(bVQ[cur][m * 64 + n]);
                    }
            g64(sS, bG1[cur], acc, m0, n0, lane);
#pragma unroll
            for (int mi = 0; mi < 2; mi++)
#pragma unroll
                for (int ni = 0; ni < 2; ni++)
#pragma unroll
                    for (int rg = 0; rg < 4; rg++) {
                        int m = m0 + mi * 16 + (lane >> 4) * 4 + rg;
                        int n = n0 + ni * 16 + (lane & 15);
                        u16 h = f2bf(acc[mi][ni][rg]);
                        sSA[m * 64 + n] = h;
                        SA[ub + m * 64 + n] = h;
                    }
        }
        __syncthreads();                  // B2 (also drains prefetch)

        // gS': S' = (S + SA.bhat + Vt.khat) * cumL[k]
        {
            f32x4 acc[2][2] = {};
            g64(sSA, bBh[cur], acc, m0, n0, lane);
            g64(bVt[cur], bKh[cur], acc, m0, n0, lane);
#pragma unroll
            for (int mi = 0; mi < 2; mi++)
#pragma unroll
                for (int ni = 0; ni < 2; ni++)
#pragma unroll
                    for (int rg = 0; rg < 4; rg++) {
                        int m = m0 + mi * 16 + (lane >> 4) * 4 + rg;
                        int n = n0 + ni * 16 + (lane & 15);
                        float sn = (acc[mi][ni][rg] + sSf[m * 64 + n]) * sCumL[cur][n];
                        sSf[m * 64 + n] = sn;
                        u16 h = f2bf(sn);
                        sS[m * 64 + n] = h;
                        if (c + 1 < NC) Sin[ub + 4096 + m * 64 + n] = h;
                    }
        }
    }
}

// ---- C: parallel Y = Rhat x Sin^T + PB x SA^T + PK x Vt^T ----
__global__ __launch_bounds__(256, 1) void k_yout(
    const u16* __restrict__ Rhat, const u16* __restrict__ Sin, const u16* __restrict__ PB,
    const u16* __restrict__ SA, const u16* __restrict__ PK, const u16* __restrict__ Vt,
    u16* __restrict__ yout) {
    __shared__ u16 sR[4096], sSin[4096], sPB[4096], sSA[4096], sPK[4096], sV[4096];
    int tid = threadIdx.x, wv = tid >> 6, lane = tid & 63;
    int unit = blockIdx.x;
    int c = unit & 15, bh = unit >> 4, h = bh & 31, b = bh >> 5;
    size_t ub = (size_t)unit * 4096;
    stage8k(Rhat + ub, sR, tid);
    stage8k(Sin + ub, sSin, tid);
    stage8k(PB + ub, sPB, tid);
    stage8k(SA + ub, sSA, tid);
    stage8k(PK + ub, sPK, tid);
    stage8k(Vt + ub, sV, tid);
    __syncthreads();
    int m0 = (wv >> 1) * 32, n0 = (wv & 1) * 32;
    f32x4 acc[2][2] = {};
    g64(sR, sSin, acc, m0, n0, lane);
    g64(sPB, sSA, acc, m0, n0, lane);
    g64(sPK, sV, acc, m0, n0, lane);
#pragma unroll
    for (int mi = 0; mi < 2; mi++)
#pragma unroll
        for (int ni = 0; ni < 2; ni++)
#pragma unroll
            for (int rg = 0; rg < 4; rg++) {
                int m = m0 + mi * 16 + (lane >> 4) * 4 + rg;   // t local
                int n = n0 + ni * 16 + (lane & 15);            // v
                size_t gi = (((size_t)b * 1024 + c * 64 + m) * 32 + h) * 64 + n;
                yout[gi] = f2bf(acc[mi][ni][rg]);
            }
}

// ---------------- GroupNorm + bonus + gate ----------------
__global__ void k_gn(const u16* __restrict__ y, const u16* __restrict__ rb, const u16* __restrict__ kb,
                     const u16* __restrict__ vb, const u16* __restrict__ gb,
                     const float* __restrict__ gn_w, const float* __restrict__ gn_b,
                     const float* __restrict__ r_k, u16* __restrict__ yg) {
    int g = blockIdx.x * 4 + (threadIdx.x >> 6);
    int lane = threadIdx.x & 63;
    size_t ix = (size_t)g * 64 + lane;
    int c = (g & (H_ - 1)) * 64 + lane;
    float yv = bf2f(y[ix]);
    float rv = bf2f(rb[ix]), kv = bf2f(kb[ix]);
    float m1 = yv, m2 = yv * yv, s = rv * kv * r_k[c];
#pragma unroll
    for (int m = 32; m >= 1; m >>= 1) {
        m1 += __shfl_xor(m1, m, 64);
        m2 += __shfl_xor(m2, m, 64);
        s  += __shfl_xor(s, m, 64);
    }
    m1 *= (1.f / 64.f);
    m2 *= (1.f / 64.f);
    float var = m2 - m1 * m1;
    float xn = (yv - m1) * rsqrtf(var + GN_EPS_C);
    xn = xn * gn_w[c] + gn_b[c];
    float out = (xn + s * bf2f(vb[ix])) * bf2f(gb[ix]);
    yg[ix] = f2bf(out);
}

__global__ __launch_bounds__(256, 1) void k_gemm(const u16* A, int lda, const u16* Bt, int ldb,
                                                 void* Out, int ldc, int Nreal, int K, int epi,
                                                 const float* aux0, const float* aux1) {
    gemm_core(A, lda, Bt, ldb, Out, ldc, Nreal, K, blockIdx.y * 128, blockIdx.x * 128, epi, aux0, aux1);
}

// ---------------- launcher ----------------
extern "C" void kernel_launch(void* const* d_in, const int* in_sizes, int n_in,
                              void* d_out, int out_size, void* d_ws, size_t ws_size,
                              hipStream_t stream) {
    const float* x      = (const float*)d_in[0];
    const float* vfirst = (const float*)d_in[1];
    const float* x_r = (const float*)d_in[2];
    const float* x_w = (const float*)d_in[3];
    const float* x_k = (const float*)d_in[4];
    const float* x_v = (const float*)d_in[5];
    const float* x_a = (const float*)d_in[6];
    const float* x_g = (const float*)d_in[7];
    const float* w0 = (const float*)d_in[8];
    const float* w1 = (const float*)d_in[9];
    const float* w2 = (const float*)d_in[10];
    const float* a0 = (const float*)d_in[11];
    const float* a1 = (const float*)d_in[12];
    const float* a2 = (const float*)d_in[13];
    const float* v0 = (const float*)d_in[14];
    const float* v1 = (const float*)d_in[15];
    const float* v2 = (const float*)d_in[16];
    const float* g1 = (const float*)d_in[17];
    const float* g2 = (const float*)d_in[18];
    const float* k_k = (const float*)d_in[19];
    const float* k_a = (const float*)d_in[20];
    const float* r_k = (const float*)d_in[21];
    const float* W_r = (const float*)d_in[22];
    const float* W_k = (const float*)d_in[23];
    const float* W_v = (const float*)d_in[24];
    const float* W_o = (const float*)d_in[25];
    const float* gn_w = (const float*)d_in[26];
    const float* gn_b = (const float*)d_in[27];
    (void)in_sizes; (void)n_in; (void)out_size; (void)ws_size;

    char* wsp = (char*)d_ws;
    size_t off = 0;
    auto alloc = [&](size_t bytes) -> char* {
        char* p = wsp + off;
        off += (bytes + 255) & ~(size_t)255;
        return p;
    };
    const size_t MAT = (size_t)BT * C_;  // 4M elements

    u16* WrT = (u16*)alloc(MAT * 2);
    u16* WkT = (u16*)alloc(MAT * 2);
    u16* WvT = (u16*)alloc(MAT * 2);
    u16* WoT = (u16*)alloc(MAT * 2);
    u16* w1T = (u16*)alloc((size_t)128 * 2048 * 2);
    u16* a1T = (u16*)alloc((size_t)128 * 2048 * 2);
    u16* v1T = (u16*)alloc((size_t)128 * 2048 * 2);
    u16* g1T = (u16*)alloc((size_t)256 * 2048 * 2);
    u16* w2T = (u16*)alloc((size_t)2048 * 96 * 2);
    u16* a2T = (u16*)alloc((size_t)2048 * 96 * 2);
    u16* v2T = (u16*)alloc((size_t)2048 * 64 * 2);
    u16* g2T = (u16*)alloc((size_t)2048 * 256 * 2);
    char* xmixR = alloc(6 * MAT * 2);          // 48MB; reused by scan scratch
    u16* xmix = (u16*)xmixR;
    u16* hbuf = (u16*)alloc((size_t)BT * 512 * 2);
    u16* rbuf = (u16*)alloc(MAT * 2);
    u16* kbuf = (u16*)alloc(MAT * 2);
    u16* vbuf = (u16*)alloc(MAT * 2);
    u16* kkbuf = (u16*)alloc(MAT * 2);
    u16* asig = (u16*)alloc(MAT * 2);
    float* wdec = (float*)alloc(MAT * 4);
    u16* gbuf = (u16*)alloc(MAT * 2);
    u16* ybuf = (u16*)alloc(MAT * 2);
    u16* ygbuf = (u16*)alloc(MAT * 2);
    const size_t UE = (size_t)UNITS * 4096;
    u16* Ahat  = (u16*)alloc(UE * 2);
    u16* Khat  = (u16*)alloc(UE * 2);
    u16* Rhat  = (u16*)alloc(UE * 2);
    u16* Vt    = (u16*)alloc(UE * 2);
    u16* BhatT = (u16*)alloc(UE * 2);
    u16* KhatT = (u16*)alloc(UE * 2);
    float* cumLg = (float*)alloc((size_t)UNITS * 64 * 4);
    // aliases: Bhat over ygbuf (dead until k_gn); PB/PK/G1T/VQM/SA/Sin over xmix (dead after k_gemm7)
    u16* Bhat = ygbuf;
    u16* PB   = (u16*)(xmixR + (size_t)0 * 1024 * 1024);
    u16* PK   = (u16*)(xmixR + (size_t)8 * 1024 * 1024);
    u16* G1T  = (u16*)(xmixR + (size_t)16 * 1024 * 1024);
    u16* VQM  = (u16*)(xmixR + (size_t)24 * 1024 * 1024);
    u16* SAb  = (u16*)(xmixR + (size_t)32 * 1024 * 1024);
    u16* Sin  = (u16*)(xmixR + (size_t)40 * 1024 * 1024);

    // 1) weight transposes
    TArgs ta;
    ta.d[0]  = {W_r, WrT, 2048, 2048};
    ta.d[1]  = {W_k, WkT, 2048, 2048};
    ta.d[2]  = {W_v, WvT, 2048, 2048};
    ta.d[3]  = {W_o, WoT, 2048, 2048};
    ta.d[4]  = {w1, w1T, 2048, 96};
    ta.d[5]  = {a1, a1T, 2048, 96};
    ta.d[6]  = {v1, v1T, 2048, 64};
    ta.d[7]  = {g1, g1T, 2048, 256};
    ta.d[8]  = {w2, w2T, 96, 2048};
    ta.d[9]  = {a2, a2T, 96, 2048};
    ta.d[10] = {v2, v2T, 64, 2048};
    ta.d[11] = {g2, g2T, 256, 2048};
    k_transpose<<<dim3(64, 64, 12), 256, 0, stream>>>(ta);

    // 2) token-shift mixes (x4 vectorized)
    k_mix<<<dim3((unsigned)(MAT / 1024)), 256, 0, stream>>>(x, x_r, x_w, x_k, x_v, x_a, x_g, xmix);

    // 3) big GEMMs r/k/v + LoRA up-projections (one dispatch)
    k_gemm7<<<dim3(16, 16, 7), 256, 0, stream>>>(xmix, WrT, WkT, WvT, w1T, a1T, v1T, g1T,
                                                 rbuf, kbuf, vbuf, hbuf);

    // 4) LoRA down-projections (one dispatch)
    k_down4<<<dim3(16, 16, 4), 256, 0, stream>>>(hbuf, w2T, a2T, v2T, g2T,
                                                 wdec, asig, vbuf, gbuf, w0, a0, v0, vfirst);

    // 5) head prep
    k_headprep<<<dim3(BT * H_ / 4), 256, 0, stream>>>(kbuf, asig, k_k, k_a, kkbuf);

    // 6) chunked scan phase A
    k_prepA<<<dim3(UNITS / 4), 256, 0, stream>>>(wdec, kkbuf, asig, kbuf, rbuf, vbuf,
                                                 Ahat, Bhat, Khat, Rhat, Vt, BhatT, KhatT, cumLg);
    k_chunkops<<<dim3(UNITS), 256, 0, stream>>>(Ahat, Bhat, Khat, Rhat, Vt, PB, PK, G1T, VQM);

    // 7) sequential phase (SA + Sin only)
    k_scanBl<<<dim3(B_ * H_), 256, 0, stream>>>(G1T, VQM, BhatT, KhatT, Vt, cumLg, SAb, Sin);

    // 8) parallel Y
    k_yout<<<dim3(UNITS), 256, 0, stream>>>(Rhat, Sin, PB, SAb, PK, Vt, ybuf);

    // 9) GroupNorm + bonus + gate
    k_gn<<<dim3(BT * H_ / 4), 256, 0, stream>>>(ybuf, rbuf, kbuf, vbuf, gbuf, gn_w, gn_b, r_k, ygbuf);

    // 10) output projection
    k_gemm<<<dim3(16, 16), 256, 0, stream>>>(ygbuf, 2048, WoT, 2048, d_out, 2048, 2048, 2048, EP_F32, nullptr, nullptr);
}

// Round 4
// 630.174 us; speedup vs baseline: 2.0646x; 1.1088x over previous
//
#include <hip/hip_runtime.h>
#include <cstdint>
#include <cstddef>

#define DI __device__ __forceinline__

typedef unsigned short u16;

// ---------------- problem constants ----------------
constexpr int B_ = 2, T_ = 1024, C_ = 2048, H_ = 32, N_ = 64;
constexpr int BT = B_ * T_;            // 2048 rows
constexpr float GN_EPS_C = 64e-5f;     // N * 1e-5
constexpr int LCH = 64;                // scan chunk length
constexpr int NC = T_ / LCH;           // 16 chunks
constexpr int UNITS = B_ * H_ * NC;    // 1024 (b,h,chunk) units

// ---------------- small helpers ----------------
DI float bf2f(u16 h) {
    union { unsigned u; float f; } x; x.u = ((unsigned)h) << 16; return x.f;
}
DI u16 f2bf(float f) {
    union { float f; unsigned u; } x; x.f = f;
    unsigned r = (x.u + 0x7fffu + ((x.u >> 16) & 1u)) >> 16;
    return (u16)r;
}
DI float sigmoidf_(float x) { return 1.f / (1.f + __expf(-x)); }

typedef __attribute__((ext_vector_type(8))) __bf16 bf16x8;
typedef __attribute__((ext_vector_type(4))) float f32x4;

DI void gload16(const void* g, void* l) {
    __builtin_amdgcn_global_load_lds(
        (const __attribute__((address_space(1))) void*)g,
        (__attribute__((address_space(3))) void*)l,
        16, 0, 0);
}

// ---------------- epilogue ids ----------------
enum { EP_BF16 = 0, EP_F32 = 1, EP_TANH = 2, EP_SIG = 3, EP_DECAY = 4, EP_ASIG = 5, EP_VMIX = 6 };

// ---------------- generic 128x128x32 bf16 MFMA GEMM core (m97 recipe) ----------------
DI void gemm_core(const u16* __restrict__ A, int lda,
                  const u16* __restrict__ Bt, int ldb,
                  void* __restrict__ Out, int ldc,
                  int Nreal, int K, int m0, int n0, int epi,
                  const float* __restrict__ aux0, const float* __restrict__ aux1) {
    __shared__ u16 lA[128 * 32];
    __shared__ u16 lB[128 * 32];
    const int tid = threadIdx.x;
    const int lane = tid & 63;
    const int wv = tid >> 6;
    const int wr = wv >> 1, wc = wv & 1;
    const int r0 = tid >> 2;
    const int cc0 = (tid & 3) * 8;

    f32x4 acc[4][4];
#pragma unroll
    for (int i = 0; i < 4; i++)
#pragma unroll
        for (int j = 0; j < 4; j++) acc[i][j] = (f32x4){0.f, 0.f, 0.f, 0.f};

    const u16* Abase = A + (size_t)(m0 + r0) * lda + cc0;
    const u16* Bbase = Bt + (size_t)(n0 + r0) * ldb + cc0;
    u16* lA0 = &lA[r0 * 32 + cc0];
    u16* lA1 = &lA[(r0 + 64) * 32 + cc0];
    u16* lB0 = &lB[r0 * 32 + cc0];
    u16* lB1 = &lB[(r0 + 64) * 32 + cc0];

    for (int k0 = 0; k0 < K; k0 += 32) {
        __syncthreads();
        gload16(Abase + k0, lA0);
        gload16(Abase + (size_t)64 * lda + k0, lA1);
        gload16(Bbase + k0, lB0);
        gload16(Bbase + (size_t)64 * ldb + k0, lB1);
        __syncthreads();
        bf16x8 af[4], bfr[4];
#pragma unroll
        for (int i = 0; i < 4; i++) {
            af[i]  = *(const bf16x8*)&lA[(wr * 64 + i * 16 + (lane & 15)) * 32 + (lane >> 4) * 8];
            bfr[i] = *(const bf16x8*)&lB[(wc * 64 + i * 16 + (lane & 15)) * 32 + (lane >> 4) * 8];
        }
#pragma unroll
        for (int mi = 0; mi < 4; mi++)
#pragma unroll
            for (int ni = 0; ni < 4; ni++)
                acc[mi][ni] = __builtin_amdgcn_mfma_f32_16x16x32_bf16(af[mi], bfr[ni], acc[mi][ni], 0, 0, 0);
    }

#pragma unroll
    for (int mi = 0; mi < 4; mi++) {
#pragma unroll
        for (int ni = 0; ni < 4; ni++) {
            int n = n0 + wc * 64 + ni * 16 + (lane & 15);
            if (n >= Nreal) continue;
#pragma unroll
            for (int rg = 0; rg < 4; rg++) {
                int m = m0 + wr * 64 + mi * 16 + (lane >> 4) * 4 + rg;
                size_t ix = (size_t)m * ldc + n;
                float f = acc[mi][ni][rg];
                switch (epi) {
                    case EP_BF16: ((u16*)Out)[ix] = f2bf(f); break;
                    case EP_F32:  ((float*)Out)[ix] = f; break;
                    case EP_TANH: ((u16*)Out)[ix] = f2bf(tanhf(f)); break;
                    case EP_SIG:  ((u16*)Out)[ix] = f2bf(sigmoidf_(f)); break;
                    case EP_DECAY: {
                        float z = -(aux0[n] + f);
                        float sp = (z > 15.f) ? z : log1pf(expf(z));
                        ((float*)Out)[ix] = expf(-expf(-0.5f - sp));
                    } break;
                    case EP_ASIG: ((u16*)Out)[ix] = f2bf(sigmoidf_(aux0[n] + f)); break;
                    case EP_VMIX: {
                        float vs = sigmoidf_(aux0[n] + f);
                        float old = bf2f(((u16*)Out)[ix]);
                        float vf = aux1[ix];
                        ((u16*)Out)[ix] = f2bf(old + (vf - old) * vs);
                    } break;
                }
            }
        }
    }
}

__global__ __launch_bounds__(256, 1) void k_gemm(const u16* A, int lda, const u16* Bt, int ldb,
                                                 void* Out, int ldc, int Nreal, int K, int epi,
                                                 const float* aux0, const float* aux1) {
    gemm_core(A, lda, Bt, ldb, Out, ldc, Nreal, K, blockIdx.y * 128, blockIdx.x * 128, epi, aux0, aux1);
}

// r/k/v projections — compile-time EP_BF16 epilogue (keep VGPR low; round-2 proven 72 us)
__global__ __launch_bounds__(256, 1) void k_gemm_rkv(const u16* xmix, const u16* WrT, const u16* WkT,
                                                     const u16* WvT, u16* rb, u16* kb, u16* vb) {
    int z = blockIdx.z;
    const int sel[3] = {0, 2, 3};  // xr, xk, xv
    const u16* A = xmix + (size_t)sel[z] * BT * C_;
    const u16* Bt = (z == 0) ? WrT : (z == 1) ? WkT : WvT;
    u16* Out = (z == 0) ? rb : (z == 1) ? kb : vb;
    gemm_core(A, C_, Bt, C_, Out, C_, C_, C_, blockIdx.y * 128, blockIdx.x * 128, EP_BF16, nullptr, nullptr);
}

// LoRA up-projections
__global__ __launch_bounds__(256, 1) void k_upproj(const u16* xmix, const u16* w1T, const u16* a1T,
                                                   const u16* v1T, const u16* g1T, u16* hbuf) {
    int z = blockIdx.z;
    int n0 = blockIdx.x * 128;
    const int npad[4]  = {128, 128, 128, 256};
    if (n0 >= npad[z]) return;
    const int sel[4]   = {1, 4, 3, 5};        // xw, xa, xv, xg
    const int nreal[4] = {96, 96, 64, 256};
    const int coff[4]  = {0, 96, 192, 256};
    const int epi[4]   = {EP_TANH, EP_BF16, EP_BF16, EP_SIG};
    const u16* Bt = (z == 0) ? w1T : (z == 1) ? a1T : (z == 2) ? v1T : g1T;
    gemm_core(xmix + (size_t)sel[z] * BT * C_, C_, Bt, C_, hbuf + coff[z], 512, nreal[z], C_,
              blockIdx.y * 128, n0, epi[z], nullptr, nullptr);
}

// ---- fused LoRA down-projections (z 0..3) ----
__global__ __launch_bounds__(256, 1) void k_down4(const u16* hbuf, const u16* w2T, const u16* a2T,
                                                  const u16* v2T, const u16* g2T,
                                                  float* wdec, u16* asig, u16* vbuf, u16* gbuf,
                                                  const float* w0, const float* a0, const float* v0,
                                                  const float* vfirst) {
    int z = blockIdx.z;
    const int Ks[4]   = {96, 96, 64, 256};
    const int coff[4] = {0, 96, 192, 256};
    const int epi[4]  = {EP_DECAY, EP_ASIG, EP_VMIX, EP_BF16};
    const u16* Bt = (z == 0) ? w2T : (z == 1) ? a2T : (z == 2) ? v2T : g2T;
    void* Out = (z == 0) ? (void*)wdec : (z == 1) ? (void*)asig : (z == 2) ? (void*)vbuf : (void*)gbuf;
    const float* aux0 = (z == 0) ? w0 : (z == 1) ? a0 : (z == 2) ? v0 : nullptr;
    const float* aux1 = (z == 2) ? vfirst : nullptr;
    gemm_core(hbuf + coff[z], 512, Bt, Ks[z], Out, 2048, 2048, Ks[z],
              blockIdx.y * 128, blockIdx.x * 128, epi[z], aux0, aux1);
}

// ---------------- weight transpose + bf16 convert ----------------
struct TDesc { const float* in; u16* out; int K; int N; };
struct TArgs4 { TDesc d[4]; };
struct TArgs8 { TDesc d[8]; };

DI void transpose_tile(TDesc dd, int k0, int n0, int tidx) {
    __shared__ float tile[32][33];
    int tx = tidx & 31, ty = tidx >> 5;
#pragma unroll
    for (int i = 0; i < 32; i += 8)
        tile[ty + i][tx] = dd.in[(size_t)(k0 + ty + i) * dd.N + (n0 + tx)];
    __syncthreads();
#pragma unroll
    for (int i = 0; i < 32; i += 8)
        dd.out[(size_t)(n0 + ty + i) * dd.K + (k0 + tx)] = f2bf(tile[tx][ty + i]);
}

__global__ void k_transpose_big(TArgs4 a) {   // 4x 2048x2048, grid (64,64,4)
    transpose_tile(a.d[blockIdx.z], blockIdx.x * 32, blockIdx.y * 32, threadIdx.x);
}

__global__ void k_transpose_sm(TArgs8 a) {    // 8 LoRA mats, grid (64,8,8)
    TDesc dd = a.d[blockIdx.z];
    int k0 = blockIdx.x * 32, n0 = blockIdx.y * 32;
    if (k0 >= dd.K || n0 >= dd.N) return;
    transpose_tile(dd, k0, n0, threadIdx.x);
}

// ---------------- token-shift mixing (x4 vectorized) ----------------
__global__ void k_mix(const float* __restrict__ x, const float* cr, const float* cw, const float* ck,
                      const float* cv, const float* ca, const float* cg, u16* __restrict__ xmix) {
    int idx = blockIdx.x * 256 + threadIdx.x;
    int base = idx * 4;
    int c4 = base & (C_ - 1);
    int bt = base >> 11;
    int t = bt & (T_ - 1);
    float4 xv = *(const float4*)(x + base);
    float4 xp = (t == 0) ? (float4){0.f, 0.f, 0.f, 0.f} : *(const float4*)(x + base - C_);
    float4 dx = {xp.x - xv.x, xp.y - xv.y, xp.z - xv.z, xp.w - xv.w};
    const size_t S = (size_t)BT * C_;
    const float* cs[6] = {cr, cw, ck, cv, ca, cg};
#pragma unroll
    for (int j = 0; j < 6; j++) {
        float4 cc = *(const float4*)(cs[j] + c4);
        ushort4 o;
        o.x = f2bf(xv.x + dx.x * cc.x);
        o.y = f2bf(xv.y + dx.y * cc.y);
        o.z = f2bf(xv.z + dx.z * cc.z);
        o.w = f2bf(xv.w + dx.w * cc.w);
        *(ushort4*)(xmix + j * S + base) = o;
    }
}

// ---------------- head prep: kk normalize + k modulation ----------------
__global__ void k_headprep(u16* __restrict__ kb, const u16* __restrict__ ab,
                           const float* __restrict__ k_k, const float* __restrict__ k_a,
                           u16* __restrict__ kkb) {
    int g = blockIdx.x * 4 + (threadIdx.x >> 6);
    int lane = threadIdx.x & 63;
    size_t ix = (size_t)g * 64 + lane;
    int c = (g & (H_ - 1)) * 64 + lane;
    float kraw = bf2f(kb[ix]);
    float av = bf2f(ab[ix]);
    float kkv = kraw * k_k[c];
    float ss = kkv * kkv;
#pragma unroll
    for (int m = 32; m >= 1; m >>= 1) ss += __shfl_xor(ss, m, 64);
    float inv = 1.f / fmaxf(sqrtf(ss), 1e-12f);
    kkb[ix] = f2bf(kkv * inv);
    kb[ix] = f2bf(kraw * (1.f + (av - 1.f) * k_a[c]));
}

// ================= chunked WKV7 scan =================
DI bf16x8 frag64(const u16* p, int row, int ks, int lane) {
    return *(const bf16x8*)&p[(row + (lane & 15)) * 64 + ks * 32 + (lane >> 4) * 8];
}

DI void g64(const u16* lA, const u16* lB, f32x4 acc[2][2], int m0, int n0, int lane) {
#pragma unroll
    for (int ks = 0; ks < 2; ks++) {
        bf16x8 a0 = frag64(lA, m0, ks, lane);
        bf16x8 a1 = frag64(lA, m0 + 16, ks, lane);
        bf16x8 b0 = frag64(lB, n0, ks, lane);
        bf16x8 b1 = frag64(lB, n0 + 16, ks, lane);
        acc[0][0] = __builtin_amdgcn_mfma_f32_16x16x32_bf16(a0, b0, acc[0][0], 0, 0, 0);
        acc[0][1] = __builtin_amdgcn_mfma_f32_16x16x32_bf16(a0, b1, acc[0][1], 0, 0, 0);
        acc[1][0] = __builtin_amdgcn_mfma_f32_16x16x32_bf16(a1, b0, acc[1][0], 0, 0, 0);
        acc[1][1] = __builtin_amdgcn_mfma_f32_16x16x32_bf16(a1, b1, acc[1][1], 0, 0, 0);
    }
}

DI void stage8k(const u16* g, u16* l, int tid) {   // 4096 u16 = 8KB
    gload16(g + tid * 8, l + tid * 8);
    gload16(g + 2048 + tid * 8, l + 2048 + tid * 8);
}

// ---- A1: cumprod + hat vectors + transposed copies ----
__global__ __launch_bounds__(256, 1) void k_prepA(
    const float* __restrict__ wdec, const u16* __restrict__ kkb, const u16* __restrict__ asig,
    const u16* __restrict__ kb, const u16* __restrict__ rb, const u16* __restrict__ vb,
    u16* __restrict__ Ahat, u16* __restrict__ Bhat, u16* __restrict__ Khat, u16* __restrict__ Rhat,
    u16* __restrict__ Vt, u16* __restrict__ BhatT, u16* __restrict__ KhatT, float* __restrict__ cumLg) {
    __shared__ u16 stg[4][3][64 * 66];
    int tid = threadIdx.x, wv = tid >> 6, lane = tid & 63;
    int unit = blockIdx.x * 4 + wv;
    int c = unit & 15, bh = unit >> 4, h = bh & 31, b = bh >> 5;
    size_t ub = (size_t)unit * 4096;
    u16* sB = stg[wv][0]; u16* sK = stg[wv][1]; u16* sV = stg[wv][2];
    float cum = 1.f;
#pragma unroll 4
    for (int t = 0; t < 64; t++) {
        size_t gi = (((size_t)b * 1024 + c * 64 + t) * 32 + h) * 64 + lane;
        float w  = wdec[gi];
        float kk = bf2f(kkb[gi]), ic = bf2f(asig[gi]), km = bf2f(kb[gi]);
        float r  = bf2f(rb[gi]),  v  = bf2f(vb[gi]);
        float cp = cum; cum = cum * w;
        float inv = 1.f / cum;
        Ahat[ub + t * 64 + lane] = f2bf(-kk * cp);
        Rhat[ub + t * 64 + lane] = f2bf(r * cum);
        u16 bh_ = f2bf(kk * ic * inv), kh_ = f2bf(km * inv);
        Bhat[ub + t * 64 + lane] = bh_;
        Khat[ub + t * 64 + lane] = kh_;
        sB[t * 66 + lane] = bh_;
        sK[t * 66 + lane] = kh_;
        sV[t * 66 + lane] = f2bf(v);
    }
    cumLg[(size_t)unit * 64 + lane] = cum;
    union U64x { u16 h[64]; uint4 q[8]; };
    {
        U64x tm;
#pragma unroll
        for (int t = 0; t < 64; t++) tm.h[t] = sB[t * 66 + lane];
        uint4* p = (uint4*)(BhatT + ub + lane * 64);
#pragma unroll
        for (int i = 0; i < 8; i++) p[i] = tm.q[i];
    }
    {
        U64x tm;
#pragma unroll
        for (int t = 0; t < 64; t++) tm.h[t] = sK[t * 66 + lane];
        uint4* p = (uint4*)(KhatT + ub + lane * 64);
#pragma unroll
        for (int i = 0; i < 8; i++) p[i] = tm.q[i];
    }
    {
        U64x tm;
#pragma unroll
        for (int t = 0; t < 64; t++) tm.h[t] = sV[t * 66 + lane];
        uint4* p = (uint4*)(Vt + ub + lane * 64);
#pragma unroll
        for (int i = 0; i < 8; i++) p[i] = tm.q[i];
    }
}

// ---- A2 fused: U -> blocked inversion -> PB/PK/Qt/VQ -> G1T/VQM ----
__global__ __launch_bounds__(256, 1) void k_chunkops(
    const u16* __restrict__ Ahat, const u16* __restrict__ Bhat, const u16* __restrict__ Khat,
    const u16* __restrict__ Rhat, const u16* __restrict__ Vt,
    u16* __restrict__ PB, u16* __restrict__ PK, u16* __restrict__ G1T, u16* __restrict__ VQM) {
    __shared__ u16 sA[4096], sB[4096], sK[4096], sR[4096], sV[4096], sQt[4096], sAT[4096];
    __shared__ float Uf[64 * 65];
    int tid = threadIdx.x, wv = tid >> 6, lane = tid & 63;
    size_t ub = (size_t)blockIdx.x * 4096;
    int m0 = (wv >> 1) * 32, n0 = (wv & 1) * 32;
    u16* sMt = sB;   // alias: sB dead after P2
    u16* sVQ = sR;   // alias: sR dead after P2

    stage8k(Ahat + ub, sA, tid);
    stage8k(Bhat + ub, sB, tid);
    stage8k(Khat + ub, sK, tid);
    stage8k(Rhat + ub, sR, tid);
    stage8k(Vt + ub, sV, tid);
    __syncthreads();

    // P1: U[s][t] (strict upper) + AhatT
    {
        f32x4 acc[2][2] = {};
        g64(sB, sA, acc, m0, n0, lane);
#pragma unroll
        for (int mi = 0; mi < 2; mi++)
#pragma unroll
            for (int ni = 0; ni < 2; ni++)
#pragma unroll
                for (int rg = 0; rg < 4; rg++) {
                    int m = m0 + mi * 16 + (lane >> 4) * 4 + rg;   // s
                    int n = n0 + ni * 16 + (lane & 15);            // t
                    Uf[m * 65 + n] = (m < n) ? acc[mi][ni][rg] : 0.f;
                }
#pragma unroll
        for (int i = 0; i < 16; i++) {
            int idx = tid * 16 + i;
            int k = idx >> 6, s = idx & 63;
            sAT[idx] = sA[s * 64 + k];
        }
    }
    __syncthreads();

    // P2: PB, PK (global) + Qt (LDS)
    {
        f32x4 a1[2][2] = {}, a2[2][2] = {}, a3[2][2] = {};
        g64(sR, sB, a1, m0, n0, lane);
        g64(sR, sK, a2, m0, n0, lane);
        g64(sA, sK, a3, m0, n0, lane);
#pragma unroll
        for (int mi = 0; mi < 2; mi++)
#pragma unroll
            for (int ni = 0; ni < 2; ni++)
#pragma unroll
                for (int rg = 0; rg < 4; rg++) {
                    int m = m0 + mi * 16 + (lane >> 4) * 4 + rg;
                    int n = n0 + ni * 16 + (lane & 15);
                    PB[ub + m * 64 + n] = f2bf((n <= m) ? a1[mi][ni][rg] : 0.f);
                    PK[ub + m * 64 + n] = f2bf((n <= m) ? a2[mi][ni][rg] : 0.f);
                    sQt[m * 64 + n] = f2bf((n < m) ? a3[mi][ni][rg] : 0.f);
                }
    }
    __syncthreads();

    // P3: blocked inversion of (I-U), in place in Uf. Blocks 16x16.
    if (lane < 16) {
        int s0 = wv * 16, t = lane;
        Uf[(s0 + 15) * 65 + (s0 + t)] = (t == 15) ? 1.f : 0.f;
        for (int s = 14; s >= 0; s--) {
            float acc = (t == s) ? 1.f : 0.f;
            for (int u = s + 1; u < 16; u++)
                acc += Uf[(s0 + s) * 65 + (s0 + u)] * Uf[(s0 + u) * 65 + (s0 + t)];
            Uf[(s0 + s) * 65 + (s0 + t)] = acc;
        }
    }
    __syncthreads();
    for (int j = 1; j <= 3; j++) {
        float Xn[4];
        int t = lane & 15, q = lane >> 4;
        bool act = (wv < j);
        if (act) {
            int i = wv;
            float Wreg[4];
#pragma unroll
            for (int ri = 0; ri < 4; ri++) {
                int r = q * 4 + ri;
                float w = 0.f;
                for (int p = i; p < j; p++)
#pragma unroll
                    for (int u = 0; u < 16; u++)
                        w += Uf[(i * 16 + r) * 65 + p * 16 + u] * Uf[(p * 16 + u) * 65 + j * 16 + t];
                Wreg[ri] = w;
            }
#pragma unroll
            for (int ri = 0; ri < 4; ri++) {
                float acc = 0.f;
#pragma unroll
                for (int u = 0; u < 16; u++)
                    acc += __shfl(Wreg[ri], (lane & 48) + u, 64) * Uf[(j * 16 + u) * 65 + (j * 16 + t)];
                Xn[ri] = acc;
            }
        }
        __syncthreads();
        if (act) {
#pragma unroll
            for (int ri = 0; ri < 4; ri++)
                Uf[(wv * 16 + q * 4 + ri) * 65 + j * 16 + t] = Xn[ri];
        }
        __syncthreads();
    }
    // sMt[t][s] = X[s][t] (bf16)
#pragma unroll
    for (int i = 0; i < 16; i++) {
        int idx = tid * 16 + i;
        int t = idx >> 6, s = idx & 63;
        sMt[idx] = f2bf((s <= t) ? Uf[s * 65 + t] : 0.f);
    }
    __syncthreads();

    // P4: VQ = Vt x Qt^T -> sVQ
    {
        f32x4 acc[2][2] = {};
        g64(sV, sQt, acc, m0, n0, lane);
#pragma unroll
        for (int mi = 0; mi < 2; mi++)
#pragma unroll
            for (int ni = 0; ni < 2; ni++)
#pragma unroll
                for (int rg = 0; rg < 4; rg++) {
                    int m = m0 + mi * 16 + (lane >> 4) * 4 + rg;
                    int n = n0 + ni * 16 + (lane & 15);
                    sVQ[m * 64 + n] = f2bf(acc[mi][ni][rg]);
                }
    }
    __syncthreads();

    // P5: VQM = VQ x X ; G1T[t][k] = sum_s X[s][t] Ahat[s][k]
    {
        f32x4 a1[2][2] = {}, a2[2][2] = {};
        g64(sVQ, sMt, a1, m0, n0, lane);
        g64(sMt, sAT, a2, m0, n0, lane);
#pragma unroll
        for (int mi = 0; mi < 2; mi++)
#pragma unroll
            for (int ni = 0; ni < 2; ni++)
#pragma unroll
                for (int rg = 0; rg < 4; rg++) {
                    int m = m0 + mi * 16 + (lane >> 4) * 4 + rg;
                    int n = n0 + ni * 16 + (lane & 15);
                    VQM[ub + m * 64 + n] = f2bf(a1[mi][ni][rg]);
                    G1T[ub + m * 64 + n] = f2bf(a2[mi][ni][rg]);
                }
    }
}

// ---- B: sequential chunk recurrence (SA + Sin only) ----
__global__ __launch_bounds__(256, 1) void k_scanBl(
    const u16* __restrict__ G1T, const u16* __restrict__ VQM, const u16* __restrict__ BhatT,
    const u16* __restrict__ KhatT, const u16* __restrict__ Vt, const float* __restrict__ cumLg,
    u16* __restrict__ SA, u16* __restrict__ Sin) {
    __shared__ u16 bG1[2][4096], bVQ[2][4096], bBh[2][4096], bKh[2][4096], bVt[2][4096];
    __shared__ u16 sSA[4096], sS[4096];
    __shared__ float sSf[4096];
    __shared__ float sCumL[2][64];

    int tid = threadIdx.x, wv = tid >> 6, lane = tid & 63;
    int bh = blockIdx.x;
    int m0 = (wv >> 1) * 32, n0 = (wv & 1) * 32;

    for (int i = tid; i < 4096; i += 256) { sSf[i] = 0.f; sS[i] = 0; }
    {   // Sin chunk 0 = zeros
        uint4 z = {0, 0, 0, 0};
        uint4* p = (uint4*)(Sin + (size_t)bh * NC * 4096);
        for (int i = tid; i < 512; i += 256) p[i] = z;
    }

    auto stage = [&](int c, int buf) {
        size_t ub = ((size_t)bh * NC + c) * 4096;
        stage8k(G1T + ub, bG1[buf], tid);
        stage8k(VQM + ub, bVQ[buf], tid);
        stage8k(BhatT + ub, bBh[buf], tid);
        stage8k(KhatT + ub, bKh[buf], tid);
        stage8k(Vt + ub, bVt[buf], tid);
        if (tid < 16) gload16(cumLg + ((size_t)bh * NC + c) * 64 + tid * 4, &sCumL[buf][tid * 4]);
    };

    stage(0, 0);
    for (int c = 0; c < NC; c++) {
        int cur = c & 1;
        __syncthreads();                  // B1: staged data + prev S' visible
        if (c + 1 < NC) stage(c + 1, 1 - cur);
        size_t ub = ((size_t)bh * NC + c) * 4096;

        // gSA: SA = S x G1T-form + VQM
        {
            f32x4 acc[2][2];
#pragma unroll
            for (int mi = 0; mi < 2; mi++)
#pragma unroll
                for (int ni = 0; ni < 2; ni++)
#pragma unroll
                    for (int rg = 0; rg < 4; rg++) {
                        int m = m0 + mi * 16 + (lane >> 4) * 4 + rg;
                        int n = n0 + ni * 16 + (lane & 15);
                        acc[mi][ni][rg] = bf2f(bVQ[cur][m * 64 + n]);
                    }
            g64(sS, bG1[cur], acc, m0, n0, lane);
#pragma unroll
            for (int mi = 0; mi < 2; mi++)
#pragma unroll
                for (int ni = 0; ni < 2; ni++)
#pragma unroll
                    for (int rg = 0; rg < 4; rg++) {
                        int m = m0 + mi * 16 + (lane >> 4) * 4 + rg;
                        int n = n0 + ni * 16 + (lane & 15);
                        u16 h = f2bf(acc[mi][ni][rg]);
                        sSA[m * 64 + n] = h;
                        SA[ub + m * 64 + n] = h;
                    }
        }
        __syncthreads();                  // B2 (also drains prefetch)

        // gS': S' = (S + SA.bhat + Vt.khat) * cumL[k]
        {
            f32x4 acc[2][2] = {};
            g64(sSA, bBh[cur], acc, m0, n0, lane);
            g64(bVt[cur], bKh[cur], acc, m0, n0, lane);
#pragma unroll
            for (int mi = 0; mi < 2; mi++)
#pragma unroll
                for (int ni = 0; ni < 2; ni++)
#pragma unroll
                    for (int rg = 0; rg < 4; rg++) {
                        int m = m0 + mi * 16 + (lane >> 4) * 4 + rg;
                        int n = n0 + ni * 16 + (lane & 15);
                        float sn = (acc[mi][ni][rg] + sSf[m * 64 + n]) * sCumL[cur][n];
                        sSf[m * 64 + n] = sn;
                        u16 h = f2bf(sn);
                        sS[m * 64 + n] = h;
                        if (c + 1 < NC) Sin[ub + 4096 + m * 64 + n] = h;
                    }
        }
    }
}

// ---- C: parallel Y = Rhat x Sin^T + PB x SA^T + PK x Vt^T ----
__global__ __launch_bounds__(256, 1) void k_yout(
    const u16* __restrict__ Rhat, const u16* __restrict__ Sin, const u16* __restrict__ PB,
    const u16* __restrict__ SA, const u16* __restrict__ PK, const u16* __restrict__ Vt,
    u16* __restrict__ yout) {
    __shared__ u16 sR[4096], sSin[4096], sPB[4096], sSA[4096], sPK[4096], sV[4096];
    int tid = threadIdx.x, wv = tid >> 6, lane = tid & 63;
    int unit = blockIdx.x;
    int c = unit & 15, bh = unit >> 4, h = bh & 31, b = bh >> 5;
    size_t ub = (size_t)unit * 4096;
    stage8k(Rhat + ub, sR, tid);
    stage8k(Sin + ub, sSin, tid);
    stage8k(PB + ub, sPB, tid);
    stage8k(SA + ub, sSA, tid);
    stage8k(PK + ub, sPK, tid);
    stage8k(Vt + ub, sV, tid);
    __syncthreads();
    int m0 = (wv >> 1) * 32, n0 = (wv & 1) * 32;
    f32x4 acc[2][2] = {};
    g64(sR, sSin, acc, m0, n0, lane);
    g64(sPB, sSA, acc, m0, n0, lane);
    g64(sPK, sV, acc, m0, n0, lane);
#pragma unroll
    for (int mi = 0; mi < 2; mi++)
#pragma unroll
        for (int ni = 0; ni < 2; ni++)
#pragma unroll
            for (int rg = 0; rg < 4; rg++) {
                int m = m0 + mi * 16 + (lane >> 4) * 4 + rg;   // t local
                int n = n0 + ni * 16 + (lane & 15);            // v
                size_t gi = (((size_t)b * 1024 + c * 64 + m) * 32 + h) * 64 + n;
                yout[gi] = f2bf(acc[mi][ni][rg]);
            }
}

// ---------------- GroupNorm + bonus + gate ----------------
__global__ void k_gn(const u16* __restrict__ y, const u16* __restrict__ rb, const u16* __restrict__ kb,
                     const u16* __restrict__ vb, const u16* __restrict__ gb,
                     const float* __restrict__ gn_w, const float* __restrict__ gn_b,
                     const float* __restrict__ r_k, u16* __restrict__ yg) {
    int g = blockIdx.x * 4 + (threadIdx.x >> 6);
    int lane = threadIdx.x & 63;
    size_t ix = (size_t)g * 64 + lane;
    int c = (g & (H_ - 1)) * 64 + lane;
    float yv = bf2f(y[ix]);
    float rv = bf2f(rb[ix]), kv = bf2f(kb[ix]);
    float m1 = yv, m2 = yv * yv, s = rv * kv * r_k[c];
#pragma unroll
    for (int m = 32; m >= 1; m >>= 1) {
        m1 += __shfl_xor(m1, m, 64);
        m2 += __shfl_xor(m2, m, 64);
        s  += __shfl_xor(s, m, 64);
    }
    m1 *= (1.f / 64.f);
    m2 *= (1.f / 64.f);
    float var = m2 - m1 * m1;
    float xn = (yv - m1) * rsqrtf(var + GN_EPS_C);
    xn = xn * gn_w[c] + gn_b[c];
    float out = (xn + s * bf2f(vb[ix])) * bf2f(gb[ix]);
    yg[ix] = f2bf(out);
}

// ---------------- launcher ----------------
extern "C" void kernel_launch(void* const* d_in, const int* in_sizes, int n_in,
                              void* d_out, int out_size, void* d_ws, size_t ws_size,
                              hipStream_t stream) {
    const float* x      = (const float*)d_in[0];
    const float* vfirst = (const float*)d_in[1];
    const float* x_r = (const float*)d_in[2];
    const float* x_w = (const float*)d_in[3];
    const float* x_k = (const float*)d_in[4];
    const float* x_v = (const float*)d_in[5];
    const float* x_a = (const float*)d_in[6];
    const float* x_g = (const float*)d_in[7];
    const float* w0 = (const float*)d_in[8];
    const float* w1 = (const float*)d_in[9];
    const float* w2 = (const float*)d_in[10];
    const float* a0 = (const float*)d_in[11];
    const float* a1 = (const float*)d_in[12];
    const float* a2 = (const float*)d_in[13];
    const float* v0 = (const float*)d_in[14];
    const float* v1 = (const float*)d_in[15];
    const float* v2 = (const float*)d_in[16];
    const float* g1 = (const float*)d_in[17];
    const float* g2 = (const float*)d_in[18];
    const float* k_k = (const float*)d_in[19];
    const float* k_a = (const float*)d_in[20];
    const float* r_k = (const float*)d_in[21];
    const float* W_r = (const float*)d_in[22];
    const float* W_k = (const float*)d_in[23];
    const float* W_v = (const float*)d_in[24];
    const float* W_o = (const float*)d_in[25];
    const float* gn_w = (const float*)d_in[26];
    const float* gn_b = (const float*)d_in[27];
    (void)in_sizes; (void)n_in; (void)out_size; (void)ws_size;

    char* wsp = (char*)d_ws;
    size_t off = 0;
    auto alloc = [&](size_t bytes) -> char* {
        char* p = wsp + off;
        off += (bytes + 255) & ~(size_t)255;
        return p;
    };
    const size_t MAT = (size_t)BT * C_;  // 4M elements

    u16* WrT = (u16*)alloc(MAT * 2);
    u16* WkT = (u16*)alloc(MAT * 2);
    u16* WvT = (u16*)alloc(MAT * 2);
    u16* WoT = (u16*)alloc(MAT * 2);
    u16* w1T = (u16*)alloc((size_t)128 * 2048 * 2);
    u16* a1T = (u16*)alloc((size_t)128 * 2048 * 2);
    u16* v1T = (u16*)alloc((size_t)128 * 2048 * 2);
    u16* g1T = (u16*)alloc((size_t)256 * 2048 * 2);
    u16* w2T = (u16*)alloc((size_t)2048 * 96 * 2);
    u16* a2T = (u16*)alloc((size_t)2048 * 96 * 2);
    u16* v2T = (u16*)alloc((size_t)2048 * 64 * 2);
    u16* g2T = (u16*)alloc((size_t)2048 * 256 * 2);
    char* xmixR = alloc(6 * MAT * 2);          // 48MB; reused by scan scratch
    u16* xmix = (u16*)xmixR;
    u16* hbuf = (u16*)alloc((size_t)BT * 512 * 2);
    u16* rbuf = (u16*)alloc(MAT * 2);
    u16* kbuf = (u16*)alloc(MAT * 2);
    u16* vbuf = (u16*)alloc(MAT * 2);
    u16* kkbuf = (u16*)alloc(MAT * 2);
    u16* asig = (u16*)alloc(MAT * 2);
    float* wdec = (float*)alloc(MAT * 4);
    u16* gbuf = (u16*)alloc(MAT * 2);
    u16* ybuf = (u16*)alloc(MAT * 2);
    u16* ygbuf = (u16*)alloc(MAT * 2);
    const size_t UE = (size_t)UNITS * 4096;
    u16* Ahat  = (u16*)alloc(UE * 2);
    u16* Khat  = (u16*)alloc(UE * 2);
    u16* Rhat  = (u16*)alloc(UE * 2);
    u16* Vt    = (u16*)alloc(UE * 2);
    u16* BhatT = (u16*)alloc(UE * 2);
    u16* KhatT = (u16*)alloc(UE * 2);
    float* cumLg = (float*)alloc((size_t)UNITS * 64 * 4);
    // aliases: Bhat over ygbuf (dead until k_gn); PB/PK/G1T/VQM/SA/Sin over xmix (dead after k_gemm_rkv)
    u16* Bhat = ygbuf;
    u16* PB   = (u16*)(xmixR + (size_t)0 * 1024 * 1024);
    u16* PK   = (u16*)(xmixR + (size_t)8 * 1024 * 1024);
    u16* G1T  = (u16*)(xmixR + (size_t)16 * 1024 * 1024);
    u16* VQM  = (u16*)(xmixR + (size_t)24 * 1024 * 1024);
    u16* SAb  = (u16*)(xmixR + (size_t)32 * 1024 * 1024);
    u16* Sin  = (u16*)(xmixR + (size_t)40 * 1024 * 1024);

    // 1) weight transposes (big 4 + LoRA 8)
    TArgs4 tb;
    tb.d[0] = {W_r, WrT, 2048, 2048};
    tb.d[1] = {W_k, WkT, 2048, 2048};
    tb.d[2] = {W_v, WvT, 2048, 2048};
    tb.d[3] = {W_o, WoT, 2048, 2048};
    k_transpose_big<<<dim3(64, 64, 4), 256, 0, stream>>>(tb);
    TArgs8 ts;
    ts.d[0] = {w1, w1T, 2048, 96};
    ts.d[1] = {a1, a1T, 2048, 96};
    ts.d[2] = {v1, v1T, 2048, 64};
    ts.d[3] = {g1, g1T, 2048, 256};
    ts.d[4] = {w2, w2T, 96, 2048};
    ts.d[5] = {a2, a2T, 96, 2048};
    ts.d[6] = {v2, v2T, 64, 2048};
    ts.d[7] = {g2, g2T, 256, 2048};
    k_transpose_sm<<<dim3(64, 64, 8), 256, 0, stream>>>(ts);

    // 2) token-shift mixes (x4 vectorized)
    k_mix<<<dim3((unsigned)(MAT / 1024)), 256, 0, stream>>>(x, x_r, x_w, x_k, x_v, x_a, x_g, xmix);

    // 3) LoRA up-projections
    k_upproj<<<dim3(2, 16, 4), 256, 0, stream>>>(xmix, w1T, a1T, v1T, g1T, hbuf);

    // 4) big GEMMs r/k/v (separate, low-VGPR path — round-2 proven)
    k_gemm_rkv<<<dim3(16, 16, 3), 256, 0, stream>>>(xmix, WrT, WkT, WvT, rbuf, kbuf, vbuf);

    // 5) LoRA down-projections (one dispatch)
    k_down4<<<dim3(16, 16, 4), 256, 0, stream>>>(hbuf, w2T, a2T, v2T, g2T,
                                                 wdec, asig, vbuf, gbuf, w0, a0, v0, vfirst);

    // 6) head prep
    k_headprep<<<dim3(BT * H_ / 4), 256, 0, stream>>>(kbuf, asig, k_k, k_a, kkbuf);

    // 7) chunked scan phase A
    k_prepA<<<dim3(UNITS / 4), 256, 0, stream>>>(wdec, kkbuf, asig, kbuf, rbuf, vbuf,
                                                 Ahat, Bhat, Khat, Rhat, Vt, BhatT, KhatT, cumLg);
    k_chunkops<<<dim3(UNITS), 256, 0, stream>>>(Ahat, Bhat, Khat, Rhat, Vt, PB, PK, G1T, VQM);

    // 8) sequential phase (SA + Sin only)
    k_scanBl<<<dim3(B_ * H_), 256, 0, stream>>>(G1T, VQM, BhatT, KhatT, Vt, cumLg, SAb, Sin);

    // 9) parallel Y
    k_yout<<<dim3(UNITS), 256, 0, stream>>>(Rhat, Sin, PB, SAb, PK, Vt, ybuf);

    // 10) GroupNorm + bonus + gate
    k_gn<<<dim3(BT * H_ / 4), 256, 0, stream>>>(ybuf, rbuf, kbuf, vbuf, gbuf, gn_w, gn_b, r_k, ygbuf);

    // 11) output projection
    k_gemm<<<dim3(16, 16), 256, 0, stream>>>(ygbuf, 2048, WoT, 2048, d_out, 2048, 2048, 2048, EP_F32, nullptr, nullptr);
}

// Round 5
// 589.694 us; speedup vs baseline: 2.2063x; 1.0686x over previous
//
#include <hip/hip_runtime.h>
#include <cstdint>
#include <cstddef>

#define DI __device__ __forceinline__

typedef unsigned short u16;

// ---------------- problem constants ----------------
constexpr int B_ = 2, T_ = 1024, C_ = 2048, H_ = 32, N_ = 64;
constexpr int BT = B_ * T_;            // 2048 rows
constexpr float GN_EPS_C = 64e-5f;     // N * 1e-5
constexpr int LCH = 64;                // scan chunk length
constexpr int NC = T_ / LCH;           // 16 chunks
constexpr int UNITS = B_ * H_ * NC;    // 1024 (b,h,chunk) units

// ---------------- small helpers ----------------
DI float bf2f(u16 h) {
    union { unsigned u; float f; } x; x.u = ((unsigned)h) << 16; return x.f;
}
DI u16 f2bf(float f) {
    union { float f; unsigned u; } x; x.f = f;
    unsigned r = (x.u + 0x7fffu + ((x.u >> 16) & 1u)) >> 16;
    return (u16)r;
}
DI float sigmoidf_(float x) { return 1.f / (1.f + __expf(-x)); }
DI float tanhf_(float x) { float e = __expf(2.f * x); return 1.f - 2.f / (e + 1.f); }

typedef __attribute__((ext_vector_type(8))) __bf16 bf16x8;
typedef __attribute__((ext_vector_type(4))) float f32x4;

DI void gload16(const void* g, void* l) {
    __builtin_amdgcn_global_load_lds(
        (const __attribute__((address_space(1))) void*)g,
        (__attribute__((address_space(3))) void*)l,
        16, 0, 0);
}

// ---------------- epilogue ids ----------------
enum { EP_BF16 = 0, EP_F32 = 1, EP_TANH = 2, EP_SIG = 3, EP_LDECAY = 4, EP_ASIG = 5, EP_VMIX = 6 };

// ---------------- generic 128x128x32 bf16 MFMA GEMM core (m97 recipe) ----------------
DI void gemm_core(const u16* __restrict__ A, int lda,
                  const u16* __restrict__ Bt, int ldb,
                  void* __restrict__ Out, int ldc,
                  int Nreal, int K, int m0, int n0, int epi,
                  const float* __restrict__ aux0, const float* __restrict__ aux1) {
    __shared__ u16 lA[128 * 32];
    __shared__ u16 lB[128 * 32];
    const int tid = threadIdx.x;
    const int lane = tid & 63;
    const int wv = tid >> 6;
    const int wr = wv >> 1, wc = wv & 1;
    const int r0 = tid >> 2;
    const int cc0 = (tid & 3) * 8;

    f32x4 acc[4][4];
#pragma unroll
    for (int i = 0; i < 4; i++)
#pragma unroll
        for (int j = 0; j < 4; j++) acc[i][j] = (f32x4){0.f, 0.f, 0.f, 0.f};

    const u16* Abase = A + (size_t)(m0 + r0) * lda + cc0;
    const u16* Bbase = Bt + (size_t)(n0 + r0) * ldb + cc0;
    u16* lA0 = &lA[r0 * 32 + cc0];
    u16* lA1 = &lA[(r0 + 64) * 32 + cc0];
    u16* lB0 = &lB[r0 * 32 + cc0];
    u16* lB1 = &lB[(r0 + 64) * 32 + cc0];

    for (int k0 = 0; k0 < K; k0 += 32) {
        __syncthreads();
        gload16(Abase + k0, lA0);
        gload16(Abase + (size_t)64 * lda + k0, lA1);
        gload16(Bbase + k0, lB0);
        gload16(Bbase + (size_t)64 * ldb + k0, lB1);
        __syncthreads();
        bf16x8 af[4], bfr[4];
#pragma unroll
        for (int i = 0; i < 4; i++) {
            af[i]  = *(const bf16x8*)&lA[(wr * 64 + i * 16 + (lane & 15)) * 32 + (lane >> 4) * 8];
            bfr[i] = *(const bf16x8*)&lB[(wc * 64 + i * 16 + (lane & 15)) * 32 + (lane >> 4) * 8];
        }
#pragma unroll
        for (int mi = 0; mi < 4; mi++)
#pragma unroll
            for (int ni = 0; ni < 4; ni++)
                acc[mi][ni] = __builtin_amdgcn_mfma_f32_16x16x32_bf16(af[mi], bfr[ni], acc[mi][ni], 0, 0, 0);
    }

#pragma unroll
    for (int mi = 0; mi < 4; mi++) {
#pragma unroll
        for (int ni = 0; ni < 4; ni++) {
            int n = n0 + wc * 64 + ni * 16 + (lane & 15);
            if (n >= Nreal) continue;
#pragma unroll
            for (int rg = 0; rg < 4; rg++) {
                int m = m0 + wr * 64 + mi * 16 + (lane >> 4) * 4 + rg;
                size_t ix = (size_t)m * ldc + n;
                float f = acc[mi][ni][rg];
                switch (epi) {
                    case EP_BF16: ((u16*)Out)[ix] = f2bf(f); break;
                    case EP_F32:  ((float*)Out)[ix] = f; break;
                    case EP_TANH: ((u16*)Out)[ix] = f2bf(tanhf_(f)); break;
                    case EP_SIG:  ((u16*)Out)[ix] = f2bf(sigmoidf_(f)); break;
                    case EP_LDECAY: {
                        // store LOG of decay: lw = -exp(-0.5 - softplus(-(w0+f)))
                        float z = -(aux0[n] + f);
                        float sp = (z > 15.f) ? z : __logf(1.f + __expf(z));
                        ((float*)Out)[ix] = -__expf(-0.5f - sp);
                    } break;
                    case EP_ASIG: ((u16*)Out)[ix] = f2bf(sigmoidf_(aux0[n] + f)); break;
                    case EP_VMIX: {
                        float vs = sigmoidf_(aux0[n] + f);
                        float old = bf2f(((u16*)Out)[ix]);
                        float vf = aux1[ix];
                        ((u16*)Out)[ix] = f2bf(old + (vf - old) * vs);
                    } break;
                }
            }
        }
    }
}

__global__ __launch_bounds__(256, 1) void k_gemm(const u16* A, int lda, const u16* Bt, int ldb,
                                                 void* Out, int ldc, int Nreal, int K, int epi,
                                                 const float* aux0, const float* aux1) {
    gemm_core(A, lda, Bt, ldb, Out, ldc, Nreal, K, blockIdx.y * 128, blockIdx.x * 128, epi, aux0, aux1);
}

// r/k/v projections — compile-time EP_BF16 epilogue (low VGPR; round-2 proven 72 us)
__global__ __launch_bounds__(256, 1) void k_gemm_rkv(const u16* xmix, const u16* WrT, const u16* WkT,
                                                     const u16* WvT, u16* rb, u16* kb, u16* vb) {
    int z = blockIdx.z;
    const int sel[3] = {0, 2, 3};  // xr, xk, xv
    const u16* A = xmix + (size_t)sel[z] * BT * C_;
    const u16* Bt = (z == 0) ? WrT : (z == 1) ? WkT : WvT;
    u16* Out = (z == 0) ? rb : (z == 1) ? kb : vb;
    gemm_core(A, C_, Bt, C_, Out, C_, C_, C_, blockIdx.y * 128, blockIdx.x * 128, EP_BF16, nullptr, nullptr);
}

// LoRA up-projections
__global__ __launch_bounds__(256, 1) void k_upproj(const u16* xmix, const u16* w1T, const u16* a1T,
                                                   const u16* v1T, const u16* g1T, u16* hbuf) {
    int z = blockIdx.z;
    int n0 = blockIdx.x * 128;
    const int npad[4]  = {128, 128, 128, 256};
    if (n0 >= npad[z]) return;
    const int sel[4]   = {1, 4, 3, 5};        // xw, xa, xv, xg
    const int nreal[4] = {96, 96, 64, 256};
    const int coff[4]  = {0, 96, 192, 256};
    const int epi[4]   = {EP_TANH, EP_BF16, EP_BF16, EP_SIG};
    const u16* Bt = (z == 0) ? w1T : (z == 1) ? a1T : (z == 2) ? v1T : g1T;
    gemm_core(xmix + (size_t)sel[z] * BT * C_, C_, Bt, C_, hbuf + coff[z], 512, nreal[z], C_,
              blockIdx.y * 128, n0, epi[z], nullptr, nullptr);
}

// ---- fused LoRA down-projections (z 0..3) ----
__global__ __launch_bounds__(256, 1) void k_down4(const u16* hbuf, const u16* w2T, const u16* a2T,
                                                  const u16* v2T, const u16* g2T,
                                                  float* lwdec, u16* asig, u16* vbuf, u16* gbuf,
                                                  const float* w0, const float* a0, const float* v0,
                                                  const float* vfirst) {
    int z = blockIdx.z;
    const int Ks[4]   = {96, 96, 64, 256};
    const int coff[4] = {0, 96, 192, 256};
    const int epi[4]  = {EP_LDECAY, EP_ASIG, EP_VMIX, EP_BF16};
    const u16* Bt = (z == 0) ? w2T : (z == 1) ? a2T : (z == 2) ? v2T : g2T;
    void* Out = (z == 0) ? (void*)lwdec : (z == 1) ? (void*)asig : (z == 2) ? (void*)vbuf : (void*)gbuf;
    const float* aux0 = (z == 0) ? w0 : (z == 1) ? a0 : (z == 2) ? v0 : nullptr;
    const float* aux1 = (z == 2) ? vfirst : nullptr;
    gemm_core(hbuf + coff[z], 512, Bt, Ks[z], Out, 2048, 2048, Ks[z],
              blockIdx.y * 128, blockIdx.x * 128, epi[z], aux0, aux1);
}

// ---------------- weight transpose + bf16 convert ----------------
struct TDesc { const float* in; u16* out; int K; int N; };
struct TArgs4 { TDesc d[4]; };
struct TArgs8 { TDesc d[8]; };

DI void transpose_tile(TDesc dd, int k0, int n0, int tidx) {
    __shared__ float tile[32][33];
    int tx = tidx & 31, ty = tidx >> 5;
#pragma unroll
    for (int i = 0; i < 32; i += 8)
        tile[ty + i][tx] = dd.in[(size_t)(k0 + ty + i) * dd.N + (n0 + tx)];
    __syncthreads();
#pragma unroll
    for (int i = 0; i < 32; i += 8)
        dd.out[(size_t)(n0 + ty + i) * dd.K + (k0 + tx)] = f2bf(tile[tx][ty + i]);
}

__global__ void k_transpose_big(TArgs4 a) {   // 4x 2048x2048, grid (64,64,4)
    transpose_tile(a.d[blockIdx.z], blockIdx.x * 32, blockIdx.y * 32, threadIdx.x);
}

__global__ void k_transpose_sm(TArgs8 a) {    // 8 LoRA mats
    TDesc dd = a.d[blockIdx.z];
    int k0 = blockIdx.x * 32, n0 = blockIdx.y * 32;
    if (k0 >= dd.K || n0 >= dd.N) return;
    transpose_tile(dd, k0, n0, threadIdx.x);
}

// ---------------- token-shift mixing (x4 vectorized) ----------------
__global__ void k_mix(const float* __restrict__ x, const float* cr, const float* cw, const float* ck,
                      const float* cv, const float* ca, const float* cg, u16* __restrict__ xmix) {
    int idx = blockIdx.x * 256 + threadIdx.x;
    int base = idx * 4;
    int c4 = base & (C_ - 1);
    int bt = base >> 11;
    int t = bt & (T_ - 1);
    float4 xv = *(const float4*)(x + base);
    float4 xp = (t == 0) ? (float4){0.f, 0.f, 0.f, 0.f} : *(const float4*)(x + base - C_);
    float4 dx = {xp.x - xv.x, xp.y - xv.y, xp.z - xv.z, xp.w - xv.w};
    const size_t S = (size_t)BT * C_;
    const float* cs[6] = {cr, cw, ck, cv, ca, cg};
#pragma unroll
    for (int j = 0; j < 6; j++) {
        float4 cc = *(const float4*)(cs[j] + c4);
        ushort4 o;
        o.x = f2bf(xv.x + dx.x * cc.x);
        o.y = f2bf(xv.y + dx.y * cc.y);
        o.z = f2bf(xv.z + dx.z * cc.z);
        o.w = f2bf(xv.w + dx.w * cc.w);
        *(ushort4*)(xmix + j * S + base) = o;
    }
}

// ================= chunked WKV7 scan =================
DI bf16x8 frag64(const u16* p, int row, int ks, int lane) {
    return *(const bf16x8*)&p[(row + (lane & 15)) * 64 + ks * 32 + (lane >> 4) * 8];
}

DI void g64(const u16* lA, const u16* lB, f32x4 acc[2][2], int m0, int n0, int lane) {
#pragma unroll
    for (int ks = 0; ks < 2; ks++) {
        bf16x8 a0 = frag64(lA, m0, ks, lane);
        bf16x8 a1 = frag64(lA, m0 + 16, ks, lane);
        bf16x8 b0 = frag64(lB, n0, ks, lane);
        bf16x8 b1 = frag64(lB, n0 + 16, ks, lane);
        acc[0][0] = __builtin_amdgcn_mfma_f32_16x16x32_bf16(a0, b0, acc[0][0], 0, 0, 0);
        acc[0][1] = __builtin_amdgcn_mfma_f32_16x16x32_bf16(a0, b1, acc[0][1], 0, 0, 0);
        acc[1][0] = __builtin_amdgcn_mfma_f32_16x16x32_bf16(a1, b0, acc[1][0], 0, 0, 0);
        acc[1][1] = __builtin_amdgcn_mfma_f32_16x16x32_bf16(a1, b1, acc[1][1], 0, 0, 0);
    }
}

DI void stage8k(const u16* g, u16* l, int tid) {   // 4096 u16 = 8KB
    gload16(g + tid * 8, l + tid * 8);
    gload16(g + 2048 + tid * 8, l + 2048 + tid * 8);
}

// ---- A1: cumsum-log decay + head prep (kk-norm, k-mod) + hat vectors + transposed copies ----
__global__ __launch_bounds__(256, 1) void k_prepA(
    const float* __restrict__ lwdec, const u16* __restrict__ asig,
    u16* __restrict__ kb, const u16* __restrict__ rb, const u16* __restrict__ vb,
    const float* __restrict__ k_k, const float* __restrict__ k_a,
    u16* __restrict__ Ahat, u16* __restrict__ Bhat, u16* __restrict__ Khat, u16* __restrict__ Rhat,
    u16* __restrict__ Vt, u16* __restrict__ BhatT, u16* __restrict__ KhatT, float* __restrict__ cumLg) {
    __shared__ u16 stg[4][3][64 * 66];
    int tid = threadIdx.x, wv = tid >> 6, lane = tid & 63;
    int unit = blockIdx.x * 4 + wv;
    int c = unit & 15, bh = unit >> 4, h = bh & 31, b = bh >> 5;
    size_t ub = (size_t)unit * 4096;
    u16* sB = stg[wv][0]; u16* sK = stg[wv][1]; u16* sV = stg[wv][2];
    int cg = h * 64 + lane;
    float kkc = k_k[cg], kac = k_a[cg];
    float cs = 0.f, cum_prev = 1.f;
#pragma unroll 4
    for (int t = 0; t < 64; t++) {
        size_t gi = (((size_t)b * 1024 + c * 64 + t) * 32 + h) * 64 + lane;
        float lw = lwdec[gi];
        float kraw = bf2f(kb[gi]);
        float ic = bf2f(asig[gi]);
        float r  = bf2f(rb[gi]),  v  = bf2f(vb[gi]);
        // head prep (was k_headprep)
        float kkv = kraw * kkc;
        float ss = kkv * kkv;
#pragma unroll
        for (int m = 32; m >= 1; m >>= 1) ss += __shfl_xor(ss, m, 64);
        float kk = kkv * (1.f / fmaxf(sqrtf(ss), 1e-12f));
        float kmod = kraw * fmaf(ic - 1.f, kac, 1.f);
        kb[gi] = f2bf(kmod);
        // decay cumprod via log-cumsum
        cs += lw;
        float cum = __expf(cs);
        float inv = __expf(-cs);
        Ahat[ub + t * 64 + lane] = f2bf(-kk * cum_prev);
        Rhat[ub + t * 64 + lane] = f2bf(r * cum);
        u16 bh_ = f2bf(kk * ic * inv), kh_ = f2bf(kmod * inv);
        Bhat[ub + t * 64 + lane] = bh_;
        Khat[ub + t * 64 + lane] = kh_;
        sB[t * 66 + lane] = bh_;
        sK[t * 66 + lane] = kh_;
        sV[t * 66 + lane] = f2bf(v);
        cum_prev = cum;
    }
    cumLg[(size_t)unit * 64 + lane] = cum_prev;
    union U64x { u16 h[64]; uint4 q[8]; };
    {
        U64x tm;
#pragma unroll
        for (int t = 0; t < 64; t++) tm.h[t] = sB[t * 66 + lane];
        uint4* p = (uint4*)(BhatT + ub + lane * 64);
#pragma unroll
        for (int i = 0; i < 8; i++) p[i] = tm.q[i];
    }
    {
        U64x tm;
#pragma unroll
        for (int t = 0; t < 64; t++) tm.h[t] = sK[t * 66 + lane];
        uint4* p = (uint4*)(KhatT + ub + lane * 64);
#pragma unroll
        for (int i = 0; i < 8; i++) p[i] = tm.q[i];
    }
    {
        U64x tm;
#pragma unroll
        for (int t = 0; t < 64; t++) tm.h[t] = sV[t * 66 + lane];
        uint4* p = (uint4*)(Vt + ub + lane * 64);
#pragma unroll
        for (int i = 0; i < 8; i++) p[i] = tm.q[i];
    }
}

// ---- A2 fused: U -> blocked inversion -> PB/PK/Qt/VQ -> G1T/VQM ----
__global__ __launch_bounds__(256, 1) void k_chunkops(
    const u16* __restrict__ Ahat, const u16* __restrict__ Bhat, const u16* __restrict__ Khat,
    const u16* __restrict__ Rhat, const u16* __restrict__ Vt,
    u16* __restrict__ PB, u16* __restrict__ PK, u16* __restrict__ G1T, u16* __restrict__ VQM) {
    __shared__ u16 sA[4096], sB[4096], sK[4096], sR[4096], sV[4096], sQt[4096], sAT[4096];
    __shared__ float Uf[64 * 65];
    int tid = threadIdx.x, wv = tid >> 6, lane = tid & 63;
    size_t ub = (size_t)blockIdx.x * 4096;
    int m0 = (wv >> 1) * 32, n0 = (wv & 1) * 32;
    u16* sMt = sB;   // alias: sB dead after P2
    u16* sVQ = sR;   // alias: sR dead after P2

    stage8k(Ahat + ub, sA, tid);
    stage8k(Bhat + ub, sB, tid);
    stage8k(Khat + ub, sK, tid);
    stage8k(Rhat + ub, sR, tid);
    stage8k(Vt + ub, sV, tid);
    __syncthreads();

    // P1: U[s][t] (strict upper) + AhatT
    {
        f32x4 acc[2][2] = {};
        g64(sB, sA, acc, m0, n0, lane);
#pragma unroll
        for (int mi = 0; mi < 2; mi++)
#pragma unroll
            for (int ni = 0; ni < 2; ni++)
#pragma unroll
                for (int rg = 0; rg < 4; rg++) {
                    int m = m0 + mi * 16 + (lane >> 4) * 4 + rg;   // s
                    int n = n0 + ni * 16 + (lane & 15);            // t
                    Uf[m * 65 + n] = (m < n) ? acc[mi][ni][rg] : 0.f;
                }
#pragma unroll
        for (int i = 0; i < 16; i++) {
            int idx = tid * 16 + i;
            int k = idx >> 6, s = idx & 63;
            sAT[idx] = sA[s * 64 + k];
        }
    }
    __syncthreads();

    // P2: PB, PK (global) + Qt (LDS)
    {
        f32x4 a1[2][2] = {}, a2[2][2] = {}, a3[2][2] = {};
        g64(sR, sB, a1, m0, n0, lane);
        g64(sR, sK, a2, m0, n0, lane);
        g64(sA, sK, a3, m0, n0, lane);
#pragma unroll
        for (int mi = 0; mi < 2; mi++)
#pragma unroll
            for (int ni = 0; ni < 2; ni++)
#pragma unroll
                for (int rg = 0; rg < 4; rg++) {
                    int m = m0 + mi * 16 + (lane >> 4) * 4 + rg;
                    int n = n0 + ni * 16 + (lane & 15);
                    PB[ub + m * 64 + n] = f2bf((n <= m) ? a1[mi][ni][rg] : 0.f);
                    PK[ub + m * 64 + n] = f2bf((n <= m) ? a2[mi][ni][rg] : 0.f);
                    sQt[m * 64 + n] = f2bf((n < m) ? a3[mi][ni][rg] : 0.f);
                }
    }
    __syncthreads();

    // P3: blocked inversion of (I-U), in place in Uf. Blocks 16x16.
    if (lane < 16) {
        int s0 = wv * 16, t = lane;
        Uf[(s0 + 15) * 65 + (s0 + t)] = (t == 15) ? 1.f : 0.f;
        for (int s = 14; s >= 0; s--) {
            float acc = (t == s) ? 1.f : 0.f;
            for (int u = s + 1; u < 16; u++)
                acc += Uf[(s0 + s) * 65 + (s0 + u)] * Uf[(s0 + u) * 65 + (s0 + t)];
            Uf[(s0 + s) * 65 + (s0 + t)] = acc;
        }
    }
    __syncthreads();
    for (int j = 1; j <= 3; j++) {
        float Xn[4];
        int t = lane & 15, q = lane >> 4;
        bool act = (wv < j);
        if (act) {
            int i = wv;
            float Wreg[4];
#pragma unroll
            for (int ri = 0; ri < 4; ri++) {
                int r = q * 4 + ri;
                float w = 0.f;
                for (int p = i; p < j; p++)
#pragma unroll
                    for (int u = 0; u < 16; u++)
                        w += Uf[(i * 16 + r) * 65 + p * 16 + u] * Uf[(p * 16 + u) * 65 + j * 16 + t];
                Wreg[ri] = w;
            }
#pragma unroll
            for (int ri = 0; ri < 4; ri++) {
                float acc = 0.f;
#pragma unroll
                for (int u = 0; u < 16; u++)
                    acc += __shfl(Wreg[ri], (lane & 48) + u, 64) * Uf[(j * 16 + u) * 65 + (j * 16 + t)];
                Xn[ri] = acc;
            }
        }
        __syncthreads();
        if (act) {
#pragma unroll
            for (int ri = 0; ri < 4; ri++)
                Uf[(wv * 16 + q * 4 + ri) * 65 + j * 16 + t] = Xn[ri];
        }
        __syncthreads();
    }
    // sMt[t][s] = X[s][t] (bf16)
#pragma unroll
    for (int i = 0; i < 16; i++) {
        int idx = tid * 16 + i;
        int t = idx >> 6, s = idx & 63;
        sMt[idx] = f2bf((s <= t) ? Uf[s * 65 + t] : 0.f);
    }
    __syncthreads();

    // P4: VQ = Vt x Qt^T -> sVQ
    {
        f32x4 acc[2][2] = {};
        g64(sV, sQt, acc, m0, n0, lane);
#pragma unroll
        for (int mi = 0; mi < 2; mi++)
#pragma unroll
            for (int ni = 0; ni < 2; ni++)
#pragma unroll
                for (int rg = 0; rg < 4; rg++) {
                    int m = m0 + mi * 16 + (lane >> 4) * 4 + rg;
                    int n = n0 + ni * 16 + (lane & 15);
                    sVQ[m * 64 + n] = f2bf(acc[mi][ni][rg]);
                }
    }
    __syncthreads();

    // P5: VQM = VQ x X ; G1T[t][k] = sum_s X[s][t] Ahat[s][k]
    {
        f32x4 a1[2][2] = {}, a2[2][2] = {};
        g64(sVQ, sMt, a1, m0, n0, lane);
        g64(sMt, sAT, a2, m0, n0, lane);
#pragma unroll
        for (int mi = 0; mi < 2; mi++)
#pragma unroll
            for (int ni = 0; ni < 2; ni++)
#pragma unroll
                for (int rg = 0; rg < 4; rg++) {
                    int m = m0 + mi * 16 + (lane >> 4) * 4 + rg;
                    int n = n0 + ni * 16 + (lane & 15);
                    VQM[ub + m * 64 + n] = f2bf(a1[mi][ni][rg]);
                    G1T[ub + m * 64 + n] = f2bf(a2[mi][ni][rg]);
                }
    }
}

// ---- B: sequential chunk recurrence (SA + Sin only) ----
__global__ __launch_bounds__(256, 1) void k_scanBl(
    const u16* __restrict__ G1T, const u16* __restrict__ VQM, const u16* __restrict__ BhatT,
    const u16* __restrict__ KhatT, const u16* __restrict__ Vt, const float* __restrict__ cumLg,
    u16* __restrict__ SA, u16* __restrict__ Sin) {
    __shared__ u16 bG1[2][4096], bVQ[2][4096], bBh[2][4096], bKh[2][4096], bVt[2][4096];
    __shared__ u16 sSA[4096], sS[4096];
    __shared__ float sSf[4096];
    __shared__ float sCumL[2][64];

    int tid = threadIdx.x, wv = tid >> 6, lane = tid & 63;
    int bh = blockIdx.x;
    int m0 = (wv >> 1) * 32, n0 = (wv & 1) * 32;

    for (int i = tid; i < 4096; i += 256) { sSf[i] = 0.f; sS[i] = 0; }
    {   // Sin chunk 0 = zeros
        uint4 z = {0, 0, 0, 0};
        uint4* p = (uint4*)(Sin + (size_t)bh * NC * 4096);
        for (int i = tid; i < 512; i += 256) p[i] = z;
    }

    auto stage = [&](int c, int buf) {
        size_t ub = ((size_t)bh * NC + c) * 4096;
        stage8k(G1T + ub, bG1[buf], tid);
        stage8k(VQM + ub, bVQ[buf], tid);
        stage8k(BhatT + ub, bBh[buf], tid);
        stage8k(KhatT + ub, bKh[buf], tid);
        stage8k(Vt + ub, bVt[buf], tid);
        if (tid < 16) gload16(cumLg + ((size_t)bh * NC + c) * 64 + tid * 4, &sCumL[buf][tid * 4]);
    };

    stage(0, 0);
    for (int c = 0; c < NC; c++) {
        int cur = c & 1;
        __syncthreads();                  // B1: staged data + prev S' visible
        if (c + 1 < NC) stage(c + 1, 1 - cur);
        size_t ub = ((size_t)bh * NC + c) * 4096;

        // gSA: SA = S x G1T-form + VQM
        {
            f32x4 acc[2][2];
#pragma unroll
            for (int mi = 0; mi < 2; mi++)
#pragma unroll
                for (int ni = 0; ni < 2; ni++)
#pragma unroll
                    for (int rg = 0; rg < 4; rg++) {
                        int m = m0 + mi * 16 + (lane >> 4) * 4 + rg;
                        int n = n0 + ni * 16 + (lane & 15);
                        acc[mi][ni][rg] = bf2f(bVQ[cur][m * 64 + n]);
                    }
            g64(sS, bG1[cur], acc, m0, n0, lane);
#pragma unroll
            for (int mi = 0; mi < 2; mi++)
#pragma unroll
                for (int ni = 0; ni < 2; ni++)
#pragma unroll
                    for (int rg = 0; rg < 4; rg++) {
                        int m = m0 + mi * 16 + (lane >> 4) * 4 + rg;
                        int n = n0 + ni * 16 + (lane & 15);
                        u16 h = f2bf(acc[mi][ni][rg]);
                        sSA[m * 64 + n] = h;
                        SA[ub + m * 64 + n] = h;
                    }
        }
        __syncthreads();                  // B2 (also drains prefetch)

        // gS': S' = (S + SA.bhat + Vt.khat) * cumL[k]
        {
            f32x4 acc[2][2] = {};
            g64(sSA, bBh[cur], acc, m0, n0, lane);
            g64(bVt[cur], bKh[cur], acc, m0, n0, lane);
#pragma unroll
            for (int mi = 0; mi < 2; mi++)
#pragma unroll
                for (int ni = 0; ni < 2; ni++)
#pragma unroll
                    for (int rg = 0; rg < 4; rg++) {
                        int m = m0 + mi * 16 + (lane >> 4) * 4 + rg;
                        int n = n0 + ni * 16 + (lane & 15);
                        float sn = (acc[mi][ni][rg] + sSf[m * 64 + n]) * sCumL[cur][n];
                        sSf[m * 64 + n] = sn;
                        u16 h = f2bf(sn);
                        sS[m * 64 + n] = h;
                        if (c + 1 < NC) Sin[ub + 4096 + m * 64 + n] = h;
                    }
        }
    }
}

// ---- C: parallel Y = Rhat x Sin^T + PB x SA^T + PK x Vt^T, fused GroupNorm+bonus+gate ----
__global__ __launch_bounds__(256, 1) void k_youtgn(
    const u16* __restrict__ Rhat, const u16* __restrict__ Sin, const u16* __restrict__ PB,
    const u16* __restrict__ SA, const u16* __restrict__ PK, const u16* __restrict__ Vt,
    const u16* __restrict__ rb, const u16* __restrict__ kb, const u16* __restrict__ vb,
    const u16* __restrict__ gb, const float* __restrict__ gn_w, const float* __restrict__ gn_b,
    const float* __restrict__ r_k, u16* __restrict__ yg) {
    __shared__ u16 sR[4096], sSin[4096], sPB[4096], sSA[4096], sPK[4096], sV[4096];
    __shared__ float sY[64 * 66];
    int tid = threadIdx.x, wv = tid >> 6, lane = tid & 63;
    int unit = blockIdx.x;
    int c = unit & 15, bh = unit >> 4, h = bh & 31, b = bh >> 5;
    size_t ub = (size_t)unit * 4096;
    stage8k(Rhat + ub, sR, tid);
    stage8k(Sin + ub, sSin, tid);
    stage8k(PB + ub, sPB, tid);
    stage8k(SA + ub, sSA, tid);
    stage8k(PK + ub, sPK, tid);
    stage8k(Vt + ub, sV, tid);
    __syncthreads();
    int m0 = (wv >> 1) * 32, n0 = (wv & 1) * 32;
    f32x4 acc[2][2] = {};
    g64(sR, sSin, acc, m0, n0, lane);
    g64(sPB, sSA, acc, m0, n0, lane);
    g64(sPK, sV, acc, m0, n0, lane);
#pragma unroll
    for (int mi = 0; mi < 2; mi++)
#pragma unroll
        for (int ni = 0; ni < 2; ni++)
#pragma unroll
            for (int rg = 0; rg < 4; rg++) {
                int m = m0 + mi * 16 + (lane >> 4) * 4 + rg;   // t local
                int n = n0 + ni * 16 + (lane & 15);            // v
                sY[m * 66 + n] = acc[mi][ni][rg];
            }
    __syncthreads();
    // GroupNorm + bonus + gate: wave wv handles t-rows [wv*16, wv*16+16), lane = channel n
    int cg = h * 64 + lane;
    float gwn = gn_w[cg], gbn = gn_b[cg], rkc = r_k[cg];
#pragma unroll 2
    for (int i = 0; i < 16; i++) {
        int t = wv * 16 + i;
        float yv = sY[t * 66 + lane];
        size_t gi = (((size_t)b * 1024 + c * 64 + t) * 32 + h) * 64 + lane;
        float rv = bf2f(rb[gi]), kv = bf2f(kb[gi]);
        float m1 = yv, m2 = yv * yv, s = rv * kv * rkc;
#pragma unroll
        for (int m = 32; m >= 1; m >>= 1) {
            m1 += __shfl_xor(m1, m, 64);
            m2 += __shfl_xor(m2, m, 64);
            s  += __shfl_xor(s, m, 64);
        }
        m1 *= (1.f / 64.f);
        m2 *= (1.f / 64.f);
        float var = m2 - m1 * m1;
        float xn = (yv - m1) * rsqrtf(var + GN_EPS_C) * gwn + gbn;
        float out = (xn + s * bf2f(vb[gi])) * bf2f(gb[gi]);
        yg[gi] = f2bf(out);
    }
}

// ---------------- launcher ----------------
extern "C" void kernel_launch(void* const* d_in, const int* in_sizes, int n_in,
                              void* d_out, int out_size, void* d_ws, size_t ws_size,
                              hipStream_t stream) {
    const float* x      = (const float*)d_in[0];
    const float* vfirst = (const float*)d_in[1];
    const float* x_r = (const float*)d_in[2];
    const float* x_w = (const float*)d_in[3];
    const float* x_k = (const float*)d_in[4];
    const float* x_v = (const float*)d_in[5];
    const float* x_a = (const float*)d_in[6];
    const float* x_g = (const float*)d_in[7];
    const float* w0 = (const float*)d_in[8];
    const float* w1 = (const float*)d_in[9];
    const float* w2 = (const float*)d_in[10];
    const float* a0 = (const float*)d_in[11];
    const float* a1 = (const float*)d_in[12];
    const float* a2 = (const float*)d_in[13];
    const float* v0 = (const float*)d_in[14];
    const float* v1 = (const float*)d_in[15];
    const float* v2 = (const float*)d_in[16];
    const float* g1 = (const float*)d_in[17];
    const float* g2 = (const float*)d_in[18];
    const float* k_k = (const float*)d_in[19];
    const float* k_a = (const float*)d_in[20];
    const float* r_k = (const float*)d_in[21];
    const float* W_r = (const float*)d_in[22];
    const float* W_k = (const float*)d_in[23];
    const float* W_v = (const float*)d_in[24];
    const float* W_o = (const float*)d_in[25];
    const float* gn_w = (const float*)d_in[26];
    const float* gn_b = (const float*)d_in[27];
    (void)in_sizes; (void)n_in; (void)out_size; (void)ws_size;

    char* wsp = (char*)d_ws;
    size_t off = 0;
    auto alloc = [&](size_t bytes) -> char* {
        char* p = wsp + off;
        off += (bytes + 255) & ~(size_t)255;
        return p;
    };
    const size_t MAT = (size_t)BT * C_;  // 4M elements

    u16* WrT = (u16*)alloc(MAT * 2);
    u16* WkT = (u16*)alloc(MAT * 2);
    u16* WvT = (u16*)alloc(MAT * 2);
    u16* WoT = (u16*)alloc(MAT * 2);
    u16* w1T = (u16*)alloc((size_t)128 * 2048 * 2);
    u16* a1T = (u16*)alloc((size_t)128 * 2048 * 2);
    u16* v1T = (u16*)alloc((size_t)128 * 2048 * 2);
    u16* g1T = (u16*)alloc((size_t)256 * 2048 * 2);
    u16* w2T = (u16*)alloc((size_t)2048 * 96 * 2);
    u16* a2T = (u16*)alloc((size_t)2048 * 96 * 2);
    u16* v2T = (u16*)alloc((size_t)2048 * 64 * 2);
    u16* g2T = (u16*)alloc((size_t)2048 * 256 * 2);
    char* xmixR = alloc(6 * MAT * 2);          // 48MB; reused by scan scratch
    u16* xmix = (u16*)xmixR;
    u16* hbuf = (u16*)alloc((size_t)BT * 512 * 2);
    u16* rbuf = (u16*)alloc(MAT * 2);
    u16* kbuf = (u16*)alloc(MAT * 2);
    u16* vbuf = (u16*)alloc(MAT * 2);
    u16* asig = (u16*)alloc(MAT * 2);
    float* lwdec = (float*)alloc(MAT * 4);
    u16* gbuf = (u16*)alloc(MAT * 2);
    u16* ygbuf = (u16*)alloc(MAT * 2);
    const size_t UE = (size_t)UNITS * 4096;
    u16* Ahat  = (u16*)alloc(UE * 2);
    u16* Khat  = (u16*)alloc(UE * 2);
    u16* Rhat  = (u16*)alloc(UE * 2);
    u16* Vt    = (u16*)alloc(UE * 2);
    u16* BhatT = (u16*)alloc(UE * 2);
    u16* KhatT = (u16*)alloc(UE * 2);
    float* cumLg = (float*)alloc((size_t)UNITS * 64 * 4);
    // aliases: Bhat over ygbuf (dead until k_youtgn); PB/PK/G1T/VQM/SA/Sin over xmix (dead after rkv)
    u16* Bhat = ygbuf;
    u16* PB   = (u16*)(xmixR + (size_t)0 * 1024 * 1024);
    u16* PK   = (u16*)(xmixR + (size_t)8 * 1024 * 1024);
    u16* G1T  = (u16*)(xmixR + (size_t)16 * 1024 * 1024);
    u16* VQM  = (u16*)(xmixR + (size_t)24 * 1024 * 1024);
    u16* SAb  = (u16*)(xmixR + (size_t)32 * 1024 * 1024);
    u16* Sin  = (u16*)(xmixR + (size_t)40 * 1024 * 1024);

    // 1) weight transposes (big 4 + LoRA 8)
    TArgs4 tb;
    tb.d[0] = {W_r, WrT, 2048, 2048};
    tb.d[1] = {W_k, WkT, 2048, 2048};
    tb.d[2] = {W_v, WvT, 2048, 2048};
    tb.d[3] = {W_o, WoT, 2048, 2048};
    k_transpose_big<<<dim3(64, 64, 4), 256, 0, stream>>>(tb);
    TArgs8 ts;
    ts.d[0] = {w1, w1T, 2048, 96};
    ts.d[1] = {a1, a1T, 2048, 96};
    ts.d[2] = {v1, v1T, 2048, 64};
    ts.d[3] = {g1, g1T, 2048, 256};
    ts.d[4] = {w2, w2T, 96, 2048};
    ts.d[5] = {a2, a2T, 96, 2048};
    ts.d[6] = {v2, v2T, 64, 2048};
    ts.d[7] = {g2, g2T, 256, 2048};
    k_transpose_sm<<<dim3(64, 64, 8), 256, 0, stream>>>(ts);

    // 2) token-shift mixes (x4 vectorized)
    k_mix<<<dim3((unsigned)(MAT / 1024)), 256, 0, stream>>>(x, x_r, x_w, x_k, x_v, x_a, x_g, xmix);

    // 3) LoRA up-projections
    k_upproj<<<dim3(2, 16, 4), 256, 0, stream>>>(xmix, w1T, a1T, v1T, g1T, hbuf);

    // 4) big GEMMs r/k/v (separate, low-VGPR path)
    k_gemm_rkv<<<dim3(16, 16, 3), 256, 0, stream>>>(xmix, WrT, WkT, WvT, rbuf, kbuf, vbuf);

    // 5) LoRA down-projections (one dispatch; fast-math epilogues, log-decay)
    k_down4<<<dim3(16, 16, 4), 256, 0, stream>>>(hbuf, w2T, a2T, v2T, g2T,
                                                 lwdec, asig, vbuf, gbuf, w0, a0, v0, vfirst);

    // 6) chunked scan phase A (head prep fused)
    k_prepA<<<dim3(UNITS / 4), 256, 0, stream>>>(lwdec, asig, kbuf, rbuf, vbuf, k_k, k_a,
                                                 Ahat, Bhat, Khat, Rhat, Vt, BhatT, KhatT, cumLg);
    k_chunkops<<<dim3(UNITS), 256, 0, stream>>>(Ahat, Bhat, Khat, Rhat, Vt, PB, PK, G1T, VQM);

    // 7) sequential phase (SA + Sin only)
    k_scanBl<<<dim3(B_ * H_), 256, 0, stream>>>(G1T, VQM, BhatT, KhatT, Vt, cumLg, SAb, Sin);

    // 8) parallel Y + GroupNorm + bonus + gate (fused)
    k_youtgn<<<dim3(UNITS), 256, 0, stream>>>(Rhat, Sin, PB, SAb, PK, Vt,
                                              rbuf, kbuf, vbuf, gbuf, gn_w, gn_b, r_k, ygbuf);

    // 9) output projection
    k_gemm<<<dim3(16, 16), 256, 0, stream>>>(ygbuf, 2048, WoT, 2048, d_out, 2048, 2048, 2048, EP_F32, nullptr, nullptr);
}